// Round 8
// baseline (642.372 us; speedup 1.0000x reference)
//
#include <hip/hip_runtime.h>
#include <hip/hip_bf16.h>
#include <stdint.h>

typedef unsigned int uint32;
typedef unsigned short u16;
typedef __attribute__((ext_vector_type(8))) short bf16x8;
typedef __attribute__((ext_vector_type(4))) float f32x4;
typedef __attribute__((ext_vector_type(2))) float f32x2;
typedef uint32 u32x4 __attribute__((ext_vector_type(4)));   // align 16 (LDS)
typedef u32x4 u32x4a __attribute__((aligned(4)));           // 4B-aligned global loads
typedef uint32 u32x2 __attribute__((ext_vector_type(2)));
typedef u32x2 u32x2a __attribute__((aligned(4)));           // 4B-aligned dwordx2

#define N_NODES 50000
#define N_EDGES 800000
#define ETOT    (N_EDGES + N_NODES)
#define F_INN   78
#define H1      10
#define D1      780
#define OUT2    128
#define NGRAPH  512
#define NEG_SLOPE 0.2f

#define NX  (N_NODES * F_INN)
#define NW1 (D1 * F_INN)
#define NW2 (OUT2 * D1)

__device__ __forceinline__ float lrelu(float v) { return v > 0.f ? v : NEG_SLOPE * v; }
__device__ __forceinline__ u16 f2bfbits(float f) {
    return __bfloat16_as_ushort(__float2bfloat16(f));
}
__device__ __forceinline__ uint32 packbf(float lo, float hi) {
    return (uint32)f2bfbits(lo) | ((uint32)f2bfbits(hi) << 16);
}
__device__ __forceinline__ f32x2 bf2(uint32 u) {
    __hip_bfloat162 b = *reinterpret_cast<__hip_bfloat162*>(&u);
    float2 t = __bfloat1622float2(b);
    return (f32x2){t.x, t.y};
}
__device__ __forceinline__ int esrc(const int* ei, int e) { return e < N_EDGES ? ei[e] : e - N_EDGES; }
__device__ __forceinline__ int edst(const int* ei, int e) { return e < N_EDGES ? ei[N_EDGES + e] : e - N_EDGES; }

// ---------------- prep: x->bf16, W1->W1X bf16 [n][k], W2->W2T bf16 [n][k] ----------------
__global__ __launch_bounds__(256) void prep_kernel(const float* __restrict__ x,
                                                   const float* __restrict__ W1,
                                                   const float* __restrict__ W2,
                                                   u16* __restrict__ xb,
                                                   u16* __restrict__ W1X,
                                                   u16* __restrict__ W2T) {
    const int total = NX + NW1 + NW2;
    for (int id = blockIdx.x * 256 + threadIdx.x; id < total; id += gridDim.x * 256) {
        if (id < NX) {
            xb[id] = f2bfbits(x[id]);
        } else if (id < NX + NW1) {
            int t = id - NX;
            int n = t / F_INN, k = t - n * F_INN;
            W1X[t] = f2bfbits(W1[k * D1 + n]);
        } else {
            int t = id - NX - NW1;
            int n = t / D1, k = t - n * D1;
            W2T[t] = f2bfbits(W2[k * OUT2 + n]);
        }
    }
}

// ---------------- prep2: VAT (32x78 bf16) + w2as/w2ad (780 f32 each) ----------------
__global__ __launch_bounds__(256) void prep2_kernel(const float* __restrict__ W1,
                                                    const float* __restrict__ a_src1,
                                                    const float* __restrict__ a_dst1,
                                                    const float* __restrict__ W2,
                                                    const float* __restrict__ a_src2,
                                                    const float* __restrict__ a_dst2,
                                                    u16* __restrict__ VAT,
                                                    float* __restrict__ w2as,
                                                    float* __restrict__ w2ad) {
    int gid = blockIdx.x * 256 + threadIdx.x;
    int gs = gridDim.x * 256;
    for (int idx = gid; idx < 32 * F_INN; idx += gs) {
        int j = idx / F_INN, k = idx - j * F_INN;
        float s = 0.f;
        if (j < 20) {
            int h = (j < 10) ? j : j - 10;
            const float* vec = ((j < 10) ? a_src1 : a_dst1) + h * F_INN;
            const float* wrow = W1 + k * D1 + h * F_INN;
            for (int f = 0; f < F_INN; ++f) s = fmaf(wrow[f], vec[f], s);
        }
        VAT[j * F_INN + k] = f2bfbits(s);
    }
    for (int c = gid; c < D1; c += gs) {
        const float* r0 = W2 + (size_t)c * OUT2;
        float s = 0.f, d = 0.f;
        for (int j = 0; j < OUT2; ++j) {
            s = fmaf(r0[j], a_src2[j], s);
            d = fmaf(r0[j], a_dst2[j], d);
        }
        w2as[c] = s;
        w2ad[c] = d;
    }
}

// ---------------- alphas1x (MFMA): xb[50000x78] @ VAT^T[78x32] -> asd1[50000x20] ----------------
#define G1S 52
__global__ __launch_bounds__(256) void alphas1x_kernel(const u16* __restrict__ xb,
                                                       const u16* __restrict__ VAT,
                                                       float* __restrict__ asd1) {
    __shared__ uint32 As[128 * G1S];
    __shared__ uint32 Bs[32 * G1S];
    int tid = threadIdx.x;
    int row0 = blockIdx.x * 128;
    const uint32* xbu = (const uint32*)xb;
    const uint32* vau = (const uint32*)VAT;

    for (int idx = tid; idx < 128 * 39; idx += 256) {
        int r = idx / 39, c = idx - r * 39;
        int gr = row0 + r;
        As[r * G1S + c] = (gr < N_NODES) ? xbu[gr * 39 + c] : 0u;
    }
    for (int idx = tid; idx < 128 * 13; idx += 256) {
        int r = idx / 13, c = 39 + (idx - r * 13);
        As[r * G1S + c] = 0u;
    }
    for (int idx = tid; idx < 32 * 39; idx += 256) {
        int n = idx / 39, c = idx - n * 39;
        Bs[n * G1S + c] = vau[n * 39 + c];
    }
    for (int idx = tid; idx < 32 * 13; idx += 256) {
        int n = idx / 13, c = 39 + (idx - n * 13);
        Bs[n * G1S + c] = 0u;
    }
    __syncthreads();

    int lane = tid & 63, wv = tid >> 6;
    int wm = wv >> 1, wn = wv & 1;
    int l15 = lane & 15, quad = lane >> 4;
    const u16* Asu = (const u16*)As;
    const u16* Bsu = (const u16*)Bs;

    f32x4 acc[4];
#pragma unroll
    for (int mi = 0; mi < 4; ++mi) acc[mi] = (f32x4){0.f, 0.f, 0.f, 0.f};

    int abase[4];
#pragma unroll
    for (int mi = 0; mi < 4; ++mi) abase[mi] = (wm * 64 + mi * 16 + l15) * 104 + quad * 8;
    int bbase = (wn * 16 + l15) * 104 + quad * 8;

#pragma unroll
    for (int ks = 0; ks < 96; ks += 32) {
        bf16x8 b = *(const bf16x8*)(Bsu + bbase + ks);
#pragma unroll
        for (int mi = 0; mi < 4; ++mi) {
            bf16x8 a = *(const bf16x8*)(Asu + abase[mi] + ks);
            acc[mi] = __builtin_amdgcn_mfma_f32_16x16x32_bf16(a, b, acc[mi], 0, 0, 0);
        }
    }

    int col = wn * 16 + l15;
#pragma unroll
    for (int mi = 0; mi < 4; ++mi)
#pragma unroll
        for (int reg = 0; reg < 4; ++reg) {
            int row = row0 + wm * 64 + mi * 16 + quad * 4 + reg;
            if (row < N_NODES && col < 20) asd1[(size_t)row * 20 + col] = acc[mi][reg];
        }
}

// ---------------- CSR build ----------------
__global__ void hist_kernel(const int* __restrict__ ei, int* __restrict__ deg) {
    int e = blockIdx.x * 256 + threadIdx.x;
    if (e < ETOT) atomicAdd(&deg[edst(ei, e)], 1);
}

__global__ __launch_bounds__(256) void scan1_kernel(const int* __restrict__ deg,
                                                    int* __restrict__ row_ptr,
                                                    int* __restrict__ bsum) {
    __shared__ int buf[256];
    int tid = threadIdx.x;
    int i = blockIdx.x * 256 + tid;
    int v = (i < N_NODES) ? deg[i] : 0;
    buf[tid] = v;
    __syncthreads();
    for (int off = 1; off < 256; off <<= 1) {
        int t = (tid >= off) ? buf[tid - off] : 0;
        __syncthreads();
        buf[tid] += t;
        __syncthreads();
    }
    if (i < N_NODES) row_ptr[i] = buf[tid] - v;
    if (tid == 255) bsum[blockIdx.x] = buf[255];
}

__global__ __launch_bounds__(256) void scan2_kernel(const int* __restrict__ bsum,
                                                    int* __restrict__ boff) {
    __shared__ int buf[256];
    int tid = threadIdx.x;
    int v = (tid < 196) ? bsum[tid] : 0;
    buf[tid] = v;
    __syncthreads();
    for (int off = 1; off < 256; off <<= 1) {
        int t = (tid >= off) ? buf[tid - off] : 0;
        __syncthreads();
        buf[tid] += t;
        __syncthreads();
    }
    if (tid < 196) boff[tid] = buf[tid] - v;
}

__global__ __launch_bounds__(256) void scan3_kernel(int* __restrict__ row_ptr,
                                                    const int* __restrict__ boff,
                                                    int* __restrict__ cursor) {
    int i = blockIdx.x * 256 + threadIdx.x;
    if (i < N_NODES) {
        int r = row_ptr[i] + boff[blockIdx.x];
        row_ptr[i] = r;
        cursor[i] = r;
    }
    if (i == 0) row_ptr[N_NODES] = ETOT;
}

__global__ void scatter_kernel(const int* __restrict__ ei, int* __restrict__ cursor,
                               int* __restrict__ src_arr, int* __restrict__ dst_arr) {
    int e = blockIdx.x * 256 + threadIdx.x;
    if (e < ETOT) {
        int d = edst(ei, e);
        int pos = atomicAdd(&cursor[d], 1);
        src_arr[pos] = esrc(ei, e);
        dst_arr[pos] = d;
    }
}

// ---------------- edge-parallel exp weights, layer 1: AoS [pos][10 bf16] (5 uints) ----------------
__global__ __launch_bounds__(256) void expw_kernel(const int* __restrict__ src_arr,
                                                   const int* __restrict__ dst_arr,
                                                   const float* __restrict__ asd1,
                                                   uint32* __restrict__ expw5) {
    int p = blockIdx.x * 256 + threadIdx.x;
    if (p >= ETOT) return;
    int s = src_arr[p], d = dst_arr[p];
    const float4* sp = (const float4*)(asd1 + (size_t)s * 20);
    float4 s01 = sp[0], s02 = sp[1];
    float2 s03 = ((const float2*)sp)[4];
    const float* dp = asd1 + (size_t)d * 20 + 10;
    float2 d01 = *(const float2*)dp;
    float4 d02 = *(const float4*)(dp + 2);
    float4 d03 = *(const float4*)(dp + 6);
    float sv[10] = {s01.x, s01.y, s01.z, s01.w, s02.x, s02.y, s02.z, s02.w, s03.x, s03.y};
    float dv[10] = {d01.x, d01.y, d02.x, d02.y, d02.z, d02.w, d03.x, d03.y, d03.z, d03.w};
    uint32 o[5];
#pragma unroll
    for (int k = 0; k < 5; ++k) {
        float w0 = __expf(lrelu(sv[2 * k] + dv[2 * k]));
        float w1 = __expf(lrelu(sv[2 * k + 1] + dv[2 * k + 1]));
        o[k] = packbf(w0, w1);
    }
#pragma unroll
    for (int k = 0; k < 5; ++k) expw5[(size_t)p * 5 + k] = o[k];
}

// ---------------- edge-parallel exp weights, layer 2 ----------------
__global__ __launch_bounds__(256) void expw2_kernel(const int* __restrict__ src_arr,
                                                    const int* __restrict__ dst_arr,
                                                    const float* __restrict__ as2,
                                                    const float* __restrict__ ad2,
                                                    float* __restrict__ w2) {
    int p = blockIdx.x * 256 + threadIdx.x;
    if (p >= ETOT) return;
    w2[p] = __expf(lrelu(as2[src_arr[p]] + ad2[dst_arr[p]]));
}

// ---------------- agg1x: Agg[n,h,f] = (1/den_h) sum_e w_eh * xb[src_e, f], one wave/node ----------------
__global__ __launch_bounds__(256) void agg1x_kernel(const int* __restrict__ row_ptr,
                                                    const int* __restrict__ src_arr,
                                                    const uint32* __restrict__ expw5,
                                                    const uint32* __restrict__ xbu,
                                                    uint32* __restrict__ aggb) {
    __shared__ uint32 rows_sh[4][32 * 40];
    __shared__ float wts_sh[4][32 * 12 + 16];
    int tid = threadIdx.x, lane = tid & 63, wv = tid >> 6;
    int i = blockIdx.x * 4 + wv;
    int rs = row_ptr[i], deg = row_ptr[i + 1] - rs;
    uint32* rows = rows_sh[wv];
    float* wts = wts_sh[wv];
    float* dsh = wts + 32 * 12;

    int hA = (6 * lane) / 39;
    int hB = (6 * lane + 5) / 39;
    int j[6];
    bool sel[6];
#pragma unroll
    for (int q = 0; q < 6; ++q) {
        int u = 6 * lane + q;
        int h = u / 39;
        j[q] = u - 39 * h;
        sel[q] = (h != hA);
    }
    bool tl = lane < 6;
    int jT = 33 + lane;

    f32x2 acc[6];
#pragma unroll
    for (int q = 0; q < 6; ++q) acc[q] = (f32x2){0.f, 0.f};
    f32x2 accT = {0.f, 0.f};
    float den[10];
#pragma unroll
    for (int h = 0; h < 10; ++h) den[h] = 0.f;

    for (int base = 0; base < deg; base += 32) {
        int cnt = min(deg - base, 32);
        int e = lane >> 1, half = lane & 1;
        if (e < cnt) {
            int sn = src_arr[rs + base + e];
            const uint32* rp = xbu + (size_t)sn * 39 + half * 20;
            uint32* lp = rows + e * 40 + half * 20;
            if (half == 0) {
#pragma unroll
                for (int t = 0; t < 5; ++t)
                    *(u32x4*)(lp + 4 * t) = *(const u32x4a*)(rp + 4 * t);
                const uint32* wp = expw5 + (size_t)(rs + base + e) * 5;
#pragma unroll
                for (int k = 0; k < 5; ++k) {
                    f32x2 w2v = bf2(wp[k]);
                    den[2 * k] += w2v.x;
                    den[2 * k + 1] += w2v.y;
                    *(f32x2*)(wts + e * 12 + 2 * k) = w2v;
                }
            } else {
#pragma unroll
                for (int t = 0; t < 4; ++t)
                    *(u32x4*)(lp + 4 * t) = *(const u32x4a*)(rp + 4 * t);
                lp[16] = rp[16];
                lp[17] = rp[17];
                lp[18] = rp[18];
            }
        }
        __builtin_amdgcn_wave_barrier();
        for (int e2 = 0; e2 < cnt; ++e2) {
            const uint32* rb = rows + e2 * 40;
            const float* wb = wts + e2 * 12;
            float wA = wb[hA], wBv = wb[hB];
#pragma unroll
            for (int q = 0; q < 6; ++q) {
                uint32 v = rb[j[q]];
                float w = sel[q] ? wBv : wA;
                acc[q] = w * bf2(v) + acc[q];
            }
            if (tl) {
                uint32 v = rb[jT];
                accT = wb[9] * bf2(v) + accT;
            }
        }
        __builtin_amdgcn_wave_barrier();
    }

#pragma unroll
    for (int off = 1; off < 64; off <<= 1)
#pragma unroll
        for (int h = 0; h < 10; ++h) den[h] += __shfl_xor(den[h], off, 64);
    if (lane < 10) dsh[lane] = den[lane];
    __builtin_amdgcn_wave_barrier();
    float rA = __builtin_amdgcn_rcpf(dsh[hA]);
    float rB = __builtin_amdgcn_rcpf(dsh[hB]);
    float r9 = __builtin_amdgcn_rcpf(dsh[9]);

    uint32* orow = aggb + (size_t)i * 390;
#pragma unroll
    for (int q = 0; q < 6; ++q) {
        f32x2 a = acc[q] * (sel[q] ? rB : rA);
        orow[6 * lane + q] = packbf(a.x, a.y);
    }
    if (tl) {
        f32x2 a = accT * r9;
        orow[384 + lane] = packbf(a.x, a.y);
    }
}

// ---------------- fused12: per 64-row block, loop heads: P=relu(Agg_h@W1_h+b) (LDS),
//                  h2 += P@W2_h (regs). Emits h2, as2, ad2. out1 never materialized. ----------------
#define FS 52
__global__ __launch_bounds__(256) void fused12_kernel(const uint32* __restrict__ aggb,
                                                      const uint32* __restrict__ w1u,
                                                      const uint32* __restrict__ w2u,
                                                      const float* __restrict__ b1,
                                                      const float* __restrict__ w2as,
                                                      const float* __restrict__ w2ad,
                                                      u16* __restrict__ h2,
                                                      float* __restrict__ as2,
                                                      float* __restrict__ ad2) {
    __shared__ uint32 Ps[64 * FS];
    __shared__ uint32 As[64 * FS];
    __shared__ uint32 W1s[80 * FS];
    __shared__ uint32 W2s[128 * FS];
    int tid = threadIdx.x;
    int row0 = blockIdx.x * 64;
    int lane = tid & 63, wv = tid >> 6;
    int l15 = lane & 15, quad = lane >> 4;
    const u16* Psu = (const u16*)Ps;
    const u16* Asu = (const u16*)As;
    const u16* W1su = (const u16*)W1s;
    const u16* W2su = (const u16*)W2s;
    u16* Pw = (u16*)Ps;

    // zero K-pads once (persist across heads; per-head stages only touch uints 0..38)
    for (int idx = tid; idx < 64 * 13; idx += 256) {
        int r = idx / 13, c = 39 + (idx - (idx / 13) * 13);
        Ps[r * FS + c] = 0u;
        As[r * FS + c] = 0u;
    }
    for (int idx = tid; idx < 80 * 13; idx += 256) {
        int r = idx / 13, c = 39 + (idx - (idx / 13) * 13);
        W1s[r * FS + c] = 0u;
    }
    for (int idx = tid; idx < 2 * FS; idx += 256) W1s[78 * FS + idx] = 0u;  // rows 78,79 fully
    for (int idx = tid; idx < 128 * 13; idx += 256) {
        int r = idx / 13, c = 39 + (idx - (idx / 13) * 13);
        W2s[r * FS + c] = 0u;
    }

    f32x4 acc2[8];
#pragma unroll
    for (int nj = 0; nj < 8; ++nj) acc2[nj] = (f32x4){0.f, 0.f, 0.f, 0.f};
    float s2p[4] = {0.f, 0.f, 0.f, 0.f};
    float d2p[4] = {0.f, 0.f, 0.f, 0.f};

    int abase = (wv * 16 + l15) * 104 + quad * 8;

    for (int h = 0; h < 10; ++h) {
        __syncthreads();
        // stage Agg head slice: 64 rows x 39 uints
        for (int idx = tid; idx < 64 * 20; idx += 256) {
            int r = idx / 20, p = idx - r * 20;
            int gr = row0 + r;
            const uint32* src = aggb + (size_t)gr * 390 + h * 39;
            if (p < 19) {
                uint32 a = 0u, b = 0u;
                if (gr < N_NODES) {
                    u32x2a v = *(const u32x2a*)(src + 2 * p);
                    a = v.x; b = v.y;
                }
                As[r * FS + 2 * p] = a;
                As[r * FS + 2 * p + 1] = b;
            } else {
                As[r * FS + 38] = (gr < N_NODES) ? src[38] : 0u;
            }
        }
        // stage W1 head: 78 rows x 39 uints
        for (int idx = tid; idx < 78 * 20; idx += 256) {
            int n = idx / 20, p = idx - n * 20;
            const uint32* src = w1u + (size_t)(h * 78 + n) * 39;
            if (p < 19) {
                u32x2a v = *(const u32x2a*)(src + 2 * p);
                W1s[n * FS + 2 * p] = v.x;
                W1s[n * FS + 2 * p + 1] = v.y;
            } else {
                W1s[n * FS + 38] = src[38];
            }
        }
        // stage W2T head k-slice: 128 rows x 39 uints
        for (int idx = tid; idx < 128 * 20; idx += 256) {
            int n = idx / 20, p = idx - n * 20;
            const uint32* src = w2u + (size_t)n * 390 + h * 39;
            if (p < 19) {
                u32x2a v = *(const u32x2a*)(src + 2 * p);
                W2s[n * FS + 2 * p] = v.x;
                W2s[n * FS + 2 * p + 1] = v.y;
            } else {
                W2s[n * FS + 38] = src[38];
            }
        }
        __syncthreads();

        // phase A: P = relu(As @ W1h + b1), + as2/ad2 partials
        f32x4 accA[5];
#pragma unroll
        for (int nj = 0; nj < 5; ++nj) accA[nj] = (f32x4){0.f, 0.f, 0.f, 0.f};
#pragma unroll
        for (int ks = 0; ks < 96; ks += 32) {
            bf16x8 a = *(const bf16x8*)(Asu + abase + ks);
#pragma unroll
            for (int nj = 0; nj < 5; ++nj) {
                bf16x8 b = *(const bf16x8*)(W1su + (nj * 16 + l15) * 104 + quad * 8 + ks);
                accA[nj] = __builtin_amdgcn_mfma_f32_16x16x32_bf16(a, b, accA[nj], 0, 0, 0);
            }
        }
#pragma unroll
        for (int nj = 0; nj < 5; ++nj) {
            int col = nj * 16 + l15;
            if (col < 78) {
                int gc = h * 78 + col;
                float bia = b1[gc], was = w2as[gc], wad = w2ad[gc];
#pragma unroll
                for (int reg = 0; reg < 4; ++reg) {
                    int r = wv * 16 + quad * 4 + reg;
                    float v = fmaxf(accA[nj][reg] + bia, 0.f);
                    Pw[r * 104 + col] = f2bfbits(v);
                    s2p[reg] = fmaf(v, was, s2p[reg]);
                    d2p[reg] = fmaf(v, wad, d2p[reg]);
                }
            }
        }
        __syncthreads();

        // phase B: acc2 += P @ W2h  (A rows are wave-private, W2s read-only)
#pragma unroll
        for (int ks = 0; ks < 96; ks += 32) {
            bf16x8 a = *(const bf16x8*)(Psu + abase + ks);
#pragma unroll
            for (int nj = 0; nj < 8; ++nj) {
                bf16x8 b = *(const bf16x8*)(W2su + (nj * 16 + l15) * 104 + quad * 8 + ks);
                acc2[nj] = __builtin_amdgcn_mfma_f32_16x16x32_bf16(a, b, acc2[nj], 0, 0, 0);
            }
        }
    }

    // epilogue: h2 store
#pragma unroll
    for (int nj = 0; nj < 8; ++nj) {
        int col = nj * 16 + l15;
#pragma unroll
        for (int reg = 0; reg < 4; ++reg) {
            int r = row0 + wv * 16 + quad * 4 + reg;
            if (r < N_NODES) h2[(size_t)r * OUT2 + col] = f2bfbits(acc2[nj][reg]);
        }
    }
    // as2/ad2: reduce over 16 cols-lanes, plain store (block owns full rows)
#pragma unroll
    for (int off = 1; off < 16; off <<= 1)
#pragma unroll
        for (int reg = 0; reg < 4; ++reg) {
            s2p[reg] += __shfl_xor(s2p[reg], off, 64);
            d2p[reg] += __shfl_xor(d2p[reg], off, 64);
        }
    if (l15 == 0) {
#pragma unroll
        for (int reg = 0; reg < 4; ++reg) {
            int r = row0 + wv * 16 + quad * 4 + reg;
            if (r < N_NODES) {
                as2[r] = s2p[reg];
                ad2[r] = d2p[reg];
            }
        }
    }
}

// ---------------- layer-2 aggregation + pool: one wave per node ----------------
__global__ __launch_bounds__(256) void agg2_kernel(const int* __restrict__ row_ptr,
                                                   const int* __restrict__ src_arr,
                                                   const float* __restrict__ w2,
                                                   const uint32* __restrict__ h2u,
                                                   const float* __restrict__ b2,
                                                   const int* __restrict__ batch,
                                                   float* __restrict__ pooled) {
    __shared__ float w_sh[4][64];
    __shared__ int src_sh[4][64];
    int tid = threadIdx.x, lane = tid & 63, wv = tid >> 6;
    int i = blockIdx.x * 4 + wv;
    int rs = row_ptr[i], deg = row_ptr[i + 1] - rs;

    f32x2 acc = {0.f, 0.f};
    float den = 0.f;
    if (deg <= 64) {
        if (lane < deg) {
            float w = w2[rs + lane];
            den = w;
            w_sh[wv][lane] = w;
            src_sh[wv][lane] = src_arr[rs + lane];
        }
        __builtin_amdgcn_wave_barrier();
#pragma unroll
        for (int off = 1; off < 64; off <<= 1) den += __shfl_xor(den, off, 64);
        float rden = __builtin_amdgcn_rcpf(den);
        int cnt = deg, eix = 0;
        for (; eix + 1 < cnt; eix += 2) {
            int s0 = src_sh[wv][eix], s1 = src_sh[wv][eix + 1];
            float w0 = w_sh[wv][eix], w1 = w_sh[wv][eix + 1];
            uint32 u0 = h2u[(size_t)s0 * 64 + lane];
            uint32 u1 = h2u[(size_t)s1 * 64 + lane];
            acc = w0 * bf2(u0) + acc;
            acc = w1 * bf2(u1) + acc;
        }
        if (eix < cnt) {
            int s0 = src_sh[wv][eix];
            float w0 = w_sh[wv][eix];
            uint32 u0 = h2u[(size_t)s0 * 64 + lane];
            acc = w0 * bf2(u0) + acc;
        }
        acc *= rden;
    } else {
        for (int eix = lane; eix < deg; eix += 64) den += w2[rs + eix];
#pragma unroll
        for (int off = 1; off < 64; off <<= 1) den += __shfl_xor(den, off, 64);
        float rden = __builtin_amdgcn_rcpf(den);
        for (int base = 0; base < deg; base += 64) {
            int cnt = min(deg - base, 64);
            if (lane < cnt) {
                w_sh[wv][lane] = w2[rs + base + lane];
                src_sh[wv][lane] = src_arr[rs + base + lane];
            }
            __builtin_amdgcn_wave_barrier();
            int eix = 0;
            for (; eix + 1 < cnt; eix += 2) {
                int s0 = src_sh[wv][eix], s1 = src_sh[wv][eix + 1];
                float w0 = w_sh[wv][eix], w1 = w_sh[wv][eix + 1];
                uint32 u0 = h2u[(size_t)s0 * 64 + lane];
                uint32 u1 = h2u[(size_t)s1 * 64 + lane];
                acc = w0 * bf2(u0) + acc;
                acc = w1 * bf2(u1) + acc;
            }
            if (eix < cnt) {
                int s0 = src_sh[wv][eix];
                float w0 = w_sh[wv][eix];
                uint32 u0 = h2u[(size_t)s0 * 64 + lane];
                acc = w0 * bf2(u0) + acc;
            }
            __builtin_amdgcn_wave_barrier();
        }
        acc *= rden;
    }
    float2 bv = ((const float2*)b2)[lane];
    float v0 = fmaxf(acc.x + bv.x, 0.f);
    float v1 = fmaxf(acc.y + bv.y, 0.f);
    int g = batch[i];
    atomicMax((int*)&pooled[g * OUT2 + 2 * lane], __float_as_int(v0));
    atomicMax((int*)&pooled[g * OUT2 + 2 * lane + 1], __float_as_int(v1));
}

// ---------------- final FC + relu ----------------
__global__ __launch_bounds__(128) void fc_kernel(const float* __restrict__ pooled,
                                                 const float* __restrict__ fcW,
                                                 const float* __restrict__ fcb,
                                                 float* __restrict__ out) {
    int g = blockIdx.x, tid = threadIdx.x;
    __shared__ float p[128];
    p[tid] = pooled[g * OUT2 + tid];
    __syncthreads();
    float acc = fcb[tid];
    for (int k = 0; k < 128; ++k) acc = fmaf(p[k], fcW[k * OUT2 + tid], acc);
    out[g * OUT2 + tid] = fmaxf(acc, 0.f);
}

extern "C" void kernel_launch(void* const* d_in, const int* in_sizes, int n_in,
                              void* d_out, int out_size, void* d_ws, size_t ws_size,
                              hipStream_t stream) {
    const float* x      = (const float*)d_in[0];
    const int*   ei     = (const int*)d_in[1];
    const int*   batch  = (const int*)d_in[2];
    const float* W1     = (const float*)d_in[4];
    const float* a_src1 = (const float*)d_in[5];
    const float* a_dst1 = (const float*)d_in[6];
    const float* b1     = (const float*)d_in[7];
    const float* W2     = (const float*)d_in[8];
    const float* a_src2 = (const float*)d_in[9];
    const float* a_dst2 = (const float*)d_in[10];
    const float* b2     = (const float*)d_in[11];
    const float* fcW    = (const float*)d_in[12];
    const float* fcb    = (const float*)d_in[13];
    float* out = (float*)d_out;

    size_t off = 0;
    char* base = (char*)d_ws;
    auto alloc = [&](size_t bytes) -> void* {
        void* p = base + off;
        off += (bytes + 255) & ~(size_t)255;
        return p;
    };
    uint32* aggb = (uint32*)alloc((size_t)N_NODES * 390 * 4);
    u16* h2     = (u16*)alloc((size_t)N_NODES * OUT2 * 2);      // also hosts xb early
    u16* xb     = h2;   // xb dead before fused12 writes h2
    float* asd1 = (float*)alloc((size_t)N_NODES * 20 * 4);
    float* as2  = (float*)alloc((size_t)N_NODES * 4);
    float* ad2  = (float*)alloc((size_t)N_NODES * 4);
    u16* W1X    = (u16*)alloc((size_t)NW1 * 2);
    u16* W2T    = (u16*)alloc((size_t)NW2 * 2);
    u16* VAT    = (u16*)alloc((size_t)32 * F_INN * 2);
    float* w2as = (float*)alloc((size_t)D1 * 4);
    float* w2ad = (float*)alloc((size_t)D1 * 4);
    float* pooled = (float*)alloc((size_t)NGRAPH * OUT2 * 4);
    int* deg     = (int*)alloc((size_t)N_NODES * 4);
    int* row_ptr = (int*)alloc((size_t)(N_NODES + 1) * 4);
    int* cursor  = (int*)alloc((size_t)N_NODES * 4);
    int* src_arr = (int*)alloc((size_t)ETOT * 4);
    int* dst_arr = (int*)alloc((size_t)ETOT * 4);
    uint32* expw5 = (uint32*)alloc((size_t)ETOT * 5 * 4);
    float* w2e   = (float*)alloc((size_t)ETOT * 4);
    int* bsum    = (int*)alloc(196 * 4);
    int* boff    = (int*)alloc(196 * 4);

    hipMemsetAsync(deg, 0, (size_t)N_NODES * 4, stream);
    hipMemsetAsync(pooled, 0, (size_t)NGRAPH * OUT2 * 4, stream);

    prep_kernel<<<2048, 256, 0, stream>>>(x, W1, W2, xb, W1X, W2T);
    prep2_kernel<<<8, 256, 0, stream>>>(W1, a_src1, a_dst1, W2, a_src2, a_dst2,
                                        VAT, w2as, w2ad);
    alphas1x_kernel<<<391, 256, 0, stream>>>(xb, VAT, asd1);
    hist_kernel<<<(ETOT + 255) / 256, 256, 0, stream>>>(ei, deg);
    scan1_kernel<<<196, 256, 0, stream>>>(deg, row_ptr, bsum);
    scan2_kernel<<<1, 256, 0, stream>>>(bsum, boff);
    scan3_kernel<<<196, 256, 0, stream>>>(row_ptr, boff, cursor);
    scatter_kernel<<<(ETOT + 255) / 256, 256, 0, stream>>>(ei, cursor, src_arr, dst_arr);
    expw_kernel<<<(ETOT + 255) / 256, 256, 0, stream>>>(src_arr, dst_arr, asd1, expw5);
    agg1x_kernel<<<N_NODES / 4, 256, 0, stream>>>(row_ptr, src_arr, expw5,
                                                  (const uint32*)xb, aggb);
    fused12_kernel<<<(N_NODES + 63) / 64, 256, 0, stream>>>(aggb, (const uint32*)W1X,
                                                            (const uint32*)W2T,
                                                            b1, w2as, w2ad,
                                                            h2, as2, ad2);
    expw2_kernel<<<(ETOT + 255) / 256, 256, 0, stream>>>(src_arr, dst_arr, as2, ad2, w2e);
    agg2_kernel<<<N_NODES / 4, 256, 0, stream>>>(row_ptr, src_arr, w2e,
                                                 (const uint32*)h2, b2, batch, pooled);
    fc_kernel<<<NGRAPH, 128, 0, stream>>>(pooled, fcW, fcb, out);
}

// Round 9
// 584.278 us; speedup vs baseline: 1.0994x; 1.0994x over previous
//
#include <hip/hip_runtime.h>
#include <hip/hip_bf16.h>
#include <stdint.h>

typedef unsigned int uint32;
typedef unsigned short u16;
typedef __attribute__((ext_vector_type(8))) short bf16x8;
typedef __attribute__((ext_vector_type(4))) float f32x4;
typedef __attribute__((ext_vector_type(2))) float f32x2;
typedef uint32 u32x4 __attribute__((ext_vector_type(4)));   // align 16 (LDS)
typedef u32x4 u32x4a __attribute__((aligned(4)));           // 4B-aligned global loads
typedef uint32 u32x2 __attribute__((ext_vector_type(2)));
typedef u32x2 u32x2a __attribute__((aligned(4)));           // 4B-aligned dwordx2

#define N_NODES 50000
#define N_EDGES 800000
#define ETOT    (N_EDGES + N_NODES)
#define F_INN   78
#define H1      10
#define D1      780
#define OUT2    128
#define NGRAPH  512
#define NEG_SLOPE 0.2f

#define NX  (N_NODES * F_INN)
#define NW1 (D1 * F_INN)
#define NW2 (OUT2 * D1)
#define PLANEU (N_NODES * 39)        // uints per head-plane (aggb / out1 uint view)

__device__ __forceinline__ float lrelu(float v) { return v > 0.f ? v : NEG_SLOPE * v; }
__device__ __forceinline__ u16 f2bfbits(float f) {
    return __bfloat16_as_ushort(__float2bfloat16(f));
}
__device__ __forceinline__ uint32 packbf(float lo, float hi) {
    return (uint32)f2bfbits(lo) | ((uint32)f2bfbits(hi) << 16);
}
__device__ __forceinline__ f32x2 bf2(uint32 u) {
    __hip_bfloat162 b = *reinterpret_cast<__hip_bfloat162*>(&u);
    float2 t = __bfloat1622float2(b);
    return (f32x2){t.x, t.y};
}
__device__ __forceinline__ int esrc(const int* ei, int e) { return e < N_EDGES ? ei[e] : e - N_EDGES; }
__device__ __forceinline__ int edst(const int* ei, int e) { return e < N_EDGES ? ei[N_EDGES + e] : e - N_EDGES; }

// ---------------- prep: x->bf16, W1->W1X bf16 [n][k], W2->W2T bf16 [n][k] ----------------
__global__ __launch_bounds__(256) void prep_kernel(const float* __restrict__ x,
                                                   const float* __restrict__ W1,
                                                   const float* __restrict__ W2,
                                                   u16* __restrict__ xb,
                                                   u16* __restrict__ W1X,
                                                   u16* __restrict__ W2T) {
    const int total = NX + NW1 + NW2;
    for (int id = blockIdx.x * 256 + threadIdx.x; id < total; id += gridDim.x * 256) {
        if (id < NX) {
            xb[id] = f2bfbits(x[id]);
        } else if (id < NX + NW1) {
            int t = id - NX;
            int n = t / F_INN, k = t - n * F_INN;
            W1X[t] = f2bfbits(W1[k * D1 + n]);
        } else {
            int t = id - NX - NW1;
            int n = t / D1, k = t - n * D1;
            W2T[t] = f2bfbits(W2[k * OUT2 + n]);
        }
    }
}

// ---------------- prep2: VAT (32x78 bf16) + w2as/w2ad (780 f32 each) ----------------
__global__ __launch_bounds__(256) void prep2_kernel(const float* __restrict__ W1,
                                                    const float* __restrict__ a_src1,
                                                    const float* __restrict__ a_dst1,
                                                    const float* __restrict__ W2,
                                                    const float* __restrict__ a_src2,
                                                    const float* __restrict__ a_dst2,
                                                    u16* __restrict__ VAT,
                                                    float* __restrict__ w2as,
                                                    float* __restrict__ w2ad) {
    int gid = blockIdx.x * 256 + threadIdx.x;
    int gs = gridDim.x * 256;
    for (int idx = gid; idx < 32 * F_INN; idx += gs) {
        int j = idx / F_INN, k = idx - j * F_INN;
        float s = 0.f;
        if (j < 20) {
            int h = (j < 10) ? j : j - 10;
            const float* vec = ((j < 10) ? a_src1 : a_dst1) + h * F_INN;
            const float* wrow = W1 + k * D1 + h * F_INN;
            for (int f = 0; f < F_INN; ++f) s = fmaf(wrow[f], vec[f], s);
        }
        VAT[j * F_INN + k] = f2bfbits(s);
    }
    for (int c = gid; c < D1; c += gs) {
        const float* r0 = W2 + (size_t)c * OUT2;
        float s = 0.f, d = 0.f;
        for (int j = 0; j < OUT2; ++j) {
            s = fmaf(r0[j], a_src2[j], s);
            d = fmaf(r0[j], a_dst2[j], d);
        }
        w2as[c] = s;
        w2ad[c] = d;
    }
}

// ---------------- alphas1x (MFMA): xb[50000x78] @ VAT^T[78x32] -> asd1[50000x20] ----------------
#define G1S 52
__global__ __launch_bounds__(256) void alphas1x_kernel(const u16* __restrict__ xb,
                                                       const u16* __restrict__ VAT,
                                                       float* __restrict__ asd1) {
    __shared__ uint32 As[128 * G1S];
    __shared__ uint32 Bs[32 * G1S];
    int tid = threadIdx.x;
    int row0 = blockIdx.x * 128;
    const uint32* xbu = (const uint32*)xb;
    const uint32* vau = (const uint32*)VAT;

    for (int idx = tid; idx < 128 * 39; idx += 256) {
        int r = idx / 39, c = idx - r * 39;
        int gr = row0 + r;
        As[r * G1S + c] = (gr < N_NODES) ? xbu[gr * 39 + c] : 0u;
    }
    for (int idx = tid; idx < 128 * 13; idx += 256) {
        int r = idx / 13, c = 39 + (idx - r * 13);
        As[r * G1S + c] = 0u;
    }
    for (int idx = tid; idx < 32 * 39; idx += 256) {
        int n = idx / 39, c = idx - n * 39;
        Bs[n * G1S + c] = vau[n * 39 + c];
    }
    for (int idx = tid; idx < 32 * 13; idx += 256) {
        int n = idx / 13, c = 39 + (idx - n * 13);
        Bs[n * G1S + c] = 0u;
    }
    __syncthreads();

    int lane = tid & 63, wv = tid >> 6;
    int wm = wv >> 1, wn = wv & 1;
    int l15 = lane & 15, quad = lane >> 4;
    const u16* Asu = (const u16*)As;
    const u16* Bsu = (const u16*)Bs;

    f32x4 acc[4];
#pragma unroll
    for (int mi = 0; mi < 4; ++mi) acc[mi] = (f32x4){0.f, 0.f, 0.f, 0.f};

    int abase[4];
#pragma unroll
    for (int mi = 0; mi < 4; ++mi) abase[mi] = (wm * 64 + mi * 16 + l15) * 104 + quad * 8;
    int bbase = (wn * 16 + l15) * 104 + quad * 8;

#pragma unroll
    for (int ks = 0; ks < 96; ks += 32) {
        bf16x8 b = *(const bf16x8*)(Bsu + bbase + ks);
#pragma unroll
        for (int mi = 0; mi < 4; ++mi) {
            bf16x8 a = *(const bf16x8*)(Asu + abase[mi] + ks);
            acc[mi] = __builtin_amdgcn_mfma_f32_16x16x32_bf16(a, b, acc[mi], 0, 0, 0);
        }
    }

    int col = wn * 16 + l15;
#pragma unroll
    for (int mi = 0; mi < 4; ++mi)
#pragma unroll
        for (int reg = 0; reg < 4; ++reg) {
            int row = row0 + wm * 64 + mi * 16 + quad * 4 + reg;
            if (row < N_NODES && col < 20) asd1[(size_t)row * 20 + col] = acc[mi][reg];
        }
}

// ---------------- CSR build ----------------
__global__ void hist_kernel(const int* __restrict__ ei, int* __restrict__ deg) {
    int e = blockIdx.x * 256 + threadIdx.x;
    if (e < ETOT) atomicAdd(&deg[edst(ei, e)], 1);
}

__global__ __launch_bounds__(256) void scan1_kernel(const int* __restrict__ deg,
                                                    int* __restrict__ row_ptr,
                                                    int* __restrict__ bsum) {
    __shared__ int buf[256];
    int tid = threadIdx.x;
    int i = blockIdx.x * 256 + tid;
    int v = (i < N_NODES) ? deg[i] : 0;
    buf[tid] = v;
    __syncthreads();
    for (int off = 1; off < 256; off <<= 1) {
        int t = (tid >= off) ? buf[tid - off] : 0;
        __syncthreads();
        buf[tid] += t;
        __syncthreads();
    }
    if (i < N_NODES) row_ptr[i] = buf[tid] - v;
    if (tid == 255) bsum[blockIdx.x] = buf[255];
}

__global__ __launch_bounds__(256) void scan2_kernel(const int* __restrict__ bsum,
                                                    int* __restrict__ boff) {
    __shared__ int buf[256];
    int tid = threadIdx.x;
    int v = (tid < 196) ? bsum[tid] : 0;
    buf[tid] = v;
    __syncthreads();
    for (int off = 1; off < 256; off <<= 1) {
        int t = (tid >= off) ? buf[tid - off] : 0;
        __syncthreads();
        buf[tid] += t;
        __syncthreads();
    }
    if (tid < 196) boff[tid] = buf[tid] - v;
}

__global__ __launch_bounds__(256) void scan3_kernel(int* __restrict__ row_ptr,
                                                    const int* __restrict__ boff,
                                                    int* __restrict__ cursor) {
    int i = blockIdx.x * 256 + threadIdx.x;
    if (i < N_NODES) {
        int r = row_ptr[i] + boff[blockIdx.x];
        row_ptr[i] = r;
        cursor[i] = r;
    }
    if (i == 0) row_ptr[N_NODES] = ETOT;
}

__global__ void scatter_kernel(const int* __restrict__ ei, int* __restrict__ cursor,
                               int* __restrict__ src_arr, int* __restrict__ dst_arr) {
    int e = blockIdx.x * 256 + threadIdx.x;
    if (e < ETOT) {
        int d = edst(ei, e);
        int pos = atomicAdd(&cursor[d], 1);
        src_arr[pos] = esrc(ei, e);
        dst_arr[pos] = d;
    }
}

// ---------------- edge-parallel exp weights, layer 1: AoS [pos][10 bf16] (5 uints) ----------------
__global__ __launch_bounds__(256) void expw_kernel(const int* __restrict__ src_arr,
                                                   const int* __restrict__ dst_arr,
                                                   const float* __restrict__ asd1,
                                                   uint32* __restrict__ expw5) {
    int p = blockIdx.x * 256 + threadIdx.x;
    if (p >= ETOT) return;
    int s = src_arr[p], d = dst_arr[p];
    const float4* sp = (const float4*)(asd1 + (size_t)s * 20);
    float4 s01 = sp[0], s02 = sp[1];
    float2 s03 = ((const float2*)sp)[4];
    const float* dp = asd1 + (size_t)d * 20 + 10;
    float2 d01 = *(const float2*)dp;
    float4 d02 = *(const float4*)(dp + 2);
    float4 d03 = *(const float4*)(dp + 6);
    float sv[10] = {s01.x, s01.y, s01.z, s01.w, s02.x, s02.y, s02.z, s02.w, s03.x, s03.y};
    float dv[10] = {d01.x, d01.y, d02.x, d02.y, d02.z, d02.w, d03.x, d03.y, d03.z, d03.w};
    uint32 o[5];
#pragma unroll
    for (int k = 0; k < 5; ++k) {
        float w0 = __expf(lrelu(sv[2 * k] + dv[2 * k]));
        float w1 = __expf(lrelu(sv[2 * k + 1] + dv[2 * k + 1]));
        o[k] = packbf(w0, w1);
    }
#pragma unroll
    for (int k = 0; k < 5; ++k) expw5[(size_t)p * 5 + k] = o[k];
}

// ---------------- edge-parallel exp weights, layer 2 ----------------
__global__ __launch_bounds__(256) void expw2_kernel(const int* __restrict__ src_arr,
                                                    const int* __restrict__ dst_arr,
                                                    const float* __restrict__ as2,
                                                    const float* __restrict__ ad2,
                                                    float* __restrict__ w2) {
    int p = blockIdx.x * 256 + threadIdx.x;
    if (p >= ETOT) return;
    w2[p] = __expf(lrelu(as2[src_arr[p]] + ad2[dst_arr[p]]));
}

// ---------------- agg1x: Agg[h][n][f] = (1/den_h) sum_e w_eh * xb[src_e, f], one wave/node ----------------
// OUTPUT IS HEAD-MAJOR: aggb[h*PLANEU + n*39 + j]
__global__ __launch_bounds__(256) void agg1x_kernel(const int* __restrict__ row_ptr,
                                                    const int* __restrict__ src_arr,
                                                    const uint32* __restrict__ expw5,
                                                    const uint32* __restrict__ xbu,
                                                    uint32* __restrict__ aggb) {
    __shared__ uint32 rows_sh[4][32 * 40];
    __shared__ float wts_sh[4][32 * 12 + 16];
    int tid = threadIdx.x, lane = tid & 63, wv = tid >> 6;
    int i = blockIdx.x * 4 + wv;
    int rs = row_ptr[i], deg = row_ptr[i + 1] - rs;
    uint32* rows = rows_sh[wv];
    float* wts = wts_sh[wv];
    float* dsh = wts + 32 * 12;

    int hA = (6 * lane) / 39;
    int hB = (6 * lane + 5) / 39;
    int j[6];
    bool sel[6];
#pragma unroll
    for (int q = 0; q < 6; ++q) {
        int u = 6 * lane + q;
        int h = u / 39;
        j[q] = u - 39 * h;
        sel[q] = (h != hA);
    }
    bool tl = lane < 6;
    int jT = 33 + lane;

    f32x2 acc[6];
#pragma unroll
    for (int q = 0; q < 6; ++q) acc[q] = (f32x2){0.f, 0.f};
    f32x2 accT = {0.f, 0.f};
    float den[10];
#pragma unroll
    for (int h = 0; h < 10; ++h) den[h] = 0.f;

    for (int base = 0; base < deg; base += 32) {
        int cnt = min(deg - base, 32);
        int e = lane >> 1, half = lane & 1;
        if (e < cnt) {
            int sn = src_arr[rs + base + e];
            const uint32* rp = xbu + (size_t)sn * 39 + half * 20;
            uint32* lp = rows + e * 40 + half * 20;
            if (half == 0) {
#pragma unroll
                for (int t = 0; t < 5; ++t)
                    *(u32x4*)(lp + 4 * t) = *(const u32x4a*)(rp + 4 * t);
                const uint32* wp = expw5 + (size_t)(rs + base + e) * 5;
#pragma unroll
                for (int k = 0; k < 5; ++k) {
                    f32x2 w2v = bf2(wp[k]);
                    den[2 * k] += w2v.x;
                    den[2 * k + 1] += w2v.y;
                    *(f32x2*)(wts + e * 12 + 2 * k) = w2v;
                }
            } else {
#pragma unroll
                for (int t = 0; t < 4; ++t)
                    *(u32x4*)(lp + 4 * t) = *(const u32x4a*)(rp + 4 * t);
                lp[16] = rp[16];
                lp[17] = rp[17];
                lp[18] = rp[18];
            }
        }
        __builtin_amdgcn_wave_barrier();
        for (int e2 = 0; e2 < cnt; ++e2) {
            const uint32* rb = rows + e2 * 40;
            const float* wb = wts + e2 * 12;
            float wA = wb[hA], wBv = wb[hB];
#pragma unroll
            for (int q = 0; q < 6; ++q) {
                uint32 v = rb[j[q]];
                float w = sel[q] ? wBv : wA;
                acc[q] = w * bf2(v) + acc[q];
            }
            if (tl) {
                uint32 v = rb[jT];
                accT = wb[9] * bf2(v) + accT;
            }
        }
        __builtin_amdgcn_wave_barrier();
    }

#pragma unroll
    for (int off = 1; off < 64; off <<= 1)
#pragma unroll
        for (int h = 0; h < 10; ++h) den[h] += __shfl_xor(den[h], off, 64);
    if (lane < 10) dsh[lane] = den[lane];
    __builtin_amdgcn_wave_barrier();
    float rA = __builtin_amdgcn_rcpf(dsh[hA]);
    float rB = __builtin_amdgcn_rcpf(dsh[hB]);
    float r9 = __builtin_amdgcn_rcpf(dsh[9]);

    size_t nbase = (size_t)i * 39;
#pragma unroll
    for (int q = 0; q < 6; ++q) {
        f32x2 a = acc[q] * (sel[q] ? rB : rA);
        int hh = sel[q] ? hB : hA;
        aggb[(size_t)hh * PLANEU + nbase + j[q]] = packbf(a.x, a.y);
    }
    if (tl) {
        f32x2 a = accT * r9;
        aggb[(size_t)9 * PLANEU + nbase + jT] = packbf(a.x, a.y);
    }
}

// ---------------- gemm1b v3: grid (391 row-blocks, 10 heads); head-major in/out ----------------
// out1[h][n][78 u16] = relu(Agg_h @ W1_h + b1); as2/ad2 via l15-reduce + atomicAdd
#define GBS 49   // LDS uint stride: 98 u16 >= 96; 49%32=17 -> conflict-free; total 40768B -> 4 blk/CU
__global__ __launch_bounds__(256) void gemm1b_kernel(const uint32* __restrict__ aggb,
                                                     const uint32* __restrict__ w1u,
                                                     const float* __restrict__ b1,
                                                     const float* __restrict__ w2as,
                                                     const float* __restrict__ w2ad,
                                                     u16* __restrict__ out1,
                                                     float* __restrict__ as2,
                                                     float* __restrict__ ad2) {
    __shared__ uint32 As[128 * GBS];
    __shared__ uint32 Bs[80 * GBS];
    int tid = threadIdx.x;
    int row0 = blockIdx.x * 128;
    int h = blockIdx.y;
    const uint32* plane = aggb + (size_t)h * PLANEU;

    // zero K-pads
    for (int idx = tid; idx < 128 * 10; idx += 256) {
        int r = idx / 10, c = 39 + (idx - (idx / 10) * 10);
        As[r * GBS + c] = 0u;
    }
    for (int idx = tid; idx < 80 * 10; idx += 256) {
        int r = idx / 10, c = 39 + (idx - (idx / 10) * 10);
        Bs[r * GBS + c] = 0u;
    }
    for (int idx = tid; idx < 2 * 39; idx += 256) {
        int r = 78 + idx / 39, c = idx - (idx / 39) * 39;
        Bs[r * GBS + c] = 0u;
    }
    // stage A: contiguous head-major rows
    for (int idx = tid; idx < 128 * 20; idx += 256) {
        int r = idx / 20, p = idx - r * 20;
        int gr = row0 + r;
        const uint32* src = plane + (size_t)gr * 39;
        if (p < 19) {
            uint32 a = 0u, b = 0u;
            if (gr < N_NODES) {
                u32x2a v = *(const u32x2a*)(src + 2 * p);
                a = v.x; b = v.y;
            }
            As[r * GBS + 2 * p] = a;
            As[r * GBS + 2 * p + 1] = b;
        } else {
            As[r * GBS + 38] = (gr < N_NODES) ? src[38] : 0u;
        }
    }
    // stage W1 head
    for (int idx = tid; idx < 78 * 20; idx += 256) {
        int n = idx / 20, p = idx - n * 20;
        const uint32* src = w1u + (size_t)(h * 78 + n) * 39;
        if (p < 19) {
            u32x2a v = *(const u32x2a*)(src + 2 * p);
            Bs[n * GBS + 2 * p] = v.x;
            Bs[n * GBS + 2 * p + 1] = v.y;
        } else {
            Bs[n * GBS + 38] = src[38];
        }
    }
    __syncthreads();

    int lane = tid & 63, wv = tid >> 6;
    int l15 = lane & 15, quad = lane >> 4;
    const u16* Asu = (const u16*)As;
    const u16* Bsu = (const u16*)Bs;

    f32x4 acc[2][5];
#pragma unroll
    for (int mi = 0; mi < 2; ++mi)
#pragma unroll
        for (int nj = 0; nj < 5; ++nj) acc[mi][nj] = (f32x4){0.f, 0.f, 0.f, 0.f};

    int abase[2], bbase[5];
#pragma unroll
    for (int mi = 0; mi < 2; ++mi) abase[mi] = (wv * 32 + mi * 16 + l15) * 98 + quad * 8;
#pragma unroll
    for (int nj = 0; nj < 5; ++nj) bbase[nj] = (nj * 16 + l15) * 98 + quad * 8;

#pragma unroll
    for (int ks = 0; ks < 96; ks += 32) {
        bf16x8 a[2], b[5];
#pragma unroll
        for (int mi = 0; mi < 2; ++mi) a[mi] = *(const bf16x8*)(Asu + abase[mi] + ks);
#pragma unroll
        for (int nj = 0; nj < 5; ++nj) b[nj] = *(const bf16x8*)(Bsu + bbase[nj] + ks);
#pragma unroll
        for (int mi = 0; mi < 2; ++mi)
#pragma unroll
            for (int nj = 0; nj < 5; ++nj)
                acc[mi][nj] = __builtin_amdgcn_mfma_f32_16x16x32_bf16(a[mi], b[nj], acc[mi][nj], 0, 0, 0);
    }

    u16* oplane = out1 + (size_t)h * N_NODES * 78;
    float s2p[2][4] = {}, d2p[2][4] = {};
#pragma unroll
    for (int mi = 0; mi < 2; ++mi) {
        int rowb = row0 + wv * 32 + mi * 16 + quad * 4;
#pragma unroll
        for (int nj = 0; nj < 5; ++nj) {
            int col = nj * 16 + l15;
            if (col < 78) {
                int gc = h * 78 + col;
                float bia = b1[gc], was = w2as[gc], wad = w2ad[gc];
#pragma unroll
                for (int reg = 0; reg < 4; ++reg) {
                    int r = rowb + reg;
                    if (r < N_NODES) {
                        float v = fmaxf(acc[mi][nj][reg] + bia, 0.f);
                        oplane[(size_t)r * 78 + col] = f2bfbits(v);
                        s2p[mi][reg] = fmaf(v, was, s2p[mi][reg]);
                        d2p[mi][reg] = fmaf(v, wad, d2p[mi][reg]);
                    }
                }
            }
        }
    }

#pragma unroll
    for (int off = 1; off < 16; off <<= 1)
#pragma unroll
        for (int mi = 0; mi < 2; ++mi)
#pragma unroll
            for (int reg = 0; reg < 4; ++reg) {
                s2p[mi][reg] += __shfl_xor(s2p[mi][reg], off, 64);
                d2p[mi][reg] += __shfl_xor(d2p[mi][reg], off, 64);
            }
    if (l15 == 0) {
#pragma unroll
        for (int mi = 0; mi < 2; ++mi) {
            int rowb = row0 + wv * 32 + mi * 16 + quad * 4;
#pragma unroll
            for (int reg = 0; reg < 4; ++reg) {
                int r = rowb + reg;
                if (r < N_NODES) {
                    atomicAdd(&as2[r], s2p[mi][reg]);
                    atomicAdd(&ad2[r], d2p[mi][reg]);
                }
            }
        }
    }
}

// ---------------- GEMM2 (MFMA): out1 head-major [h][n][39u] @ W2[780x128] -> h2 bf16 ----------------
#define G2S 36
__global__ __launch_bounds__(256) void gemm2_mfma(const uint32* __restrict__ o1u,
                                                  const u16* __restrict__ W2T,
                                                  u16* __restrict__ h2) {
    __shared__ uint32 As[64 * G2S];
    __shared__ uint32 Bs[128 * G2S];
    int tid = threadIdx.x;
    int row0 = blockIdx.x * 64;
    const uint32* w2u = (const uint32*)W2T;

    int lane = tid & 63, wv = tid >> 6;
    int wm = wv >> 1, wn = wv & 1;
    int l15 = lane & 15, quad = lane >> 4;
    const u16* Asu = (const u16*)As;
    const u16* Bsu = (const u16*)Bs;

    f32x4 acc[2][4];
#pragma unroll
    for (int mi = 0; mi < 2; ++mi)
#pragma unroll
        for (int nj = 0; nj < 4; ++nj) acc[mi][nj] = (f32x4){0.f, 0.f, 0.f, 0.f};

    int abase[2], bbase[4];
#pragma unroll
    for (int mi = 0; mi < 2; ++mi) abase[mi] = (wm * 32 + mi * 16 + l15) * 72 + quad * 8;
#pragma unroll
    for (int nj = 0; nj < 4; ++nj) bbase[nj] = (wn * 64 + nj * 16 + l15) * 72 + quad * 8;

    for (int s = 0; s < 13; ++s) {
        int k0h = s * 32;
        for (int idx = tid; idx < 64 * 32; idx += 256) {
            int r = idx >> 5, c = idx & 31;
            int gr = row0 + r;
            int k = k0h + c;
            uint32 v = 0u;
            if (gr < N_NODES && k < 390) {
                int hh = (k * 1681) >> 16;            // floor(k/39), exact for k<390
                v = o1u[(size_t)hh * PLANEU + (size_t)gr * 39 + (k - 39 * hh)];
            }
            As[r * G2S + c] = v;
        }
        for (int idx = tid; idx < 128 * 32; idx += 256) {
            int n = idx >> 5, c = idx & 31;
            Bs[n * G2S + c] = ((k0h + c) < 390) ? w2u[(size_t)n * 390 + k0h + c] : 0u;
        }
        __syncthreads();
#pragma unroll
        for (int ks = 0; ks < 64; ks += 32) {
            bf16x8 a[2], b[4];
#pragma unroll
            for (int mi = 0; mi < 2; ++mi) a[mi] = *(const bf16x8*)(Asu + abase[mi] + ks);
#pragma unroll
            for (int nj = 0; nj < 4; ++nj) b[nj] = *(const bf16x8*)(Bsu + bbase[nj] + ks);
#pragma unroll
            for (int mi = 0; mi < 2; ++mi)
#pragma unroll
                for (int nj = 0; nj < 4; ++nj)
                    acc[mi][nj] = __builtin_amdgcn_mfma_f32_16x16x32_bf16(a[mi], b[nj], acc[mi][nj], 0, 0, 0);
        }
        __syncthreads();
    }

#pragma unroll
    for (int mi = 0; mi < 2; ++mi)
#pragma unroll
        for (int nj = 0; nj < 4; ++nj)
#pragma unroll
            for (int reg = 0; reg < 4; ++reg) {
                int row = row0 + wm * 32 + mi * 16 + quad * 4 + reg;
                int col = wn * 64 + nj * 16 + l15;
                if (row < N_NODES)
                    h2[(size_t)row * OUT2 + col] = f2bfbits(acc[mi][nj][reg]);
            }
}

// ---------------- layer-2 aggregation + pool: one wave per node ----------------
__global__ __launch_bounds__(256) void agg2_kernel(const int* __restrict__ row_ptr,
                                                   const int* __restrict__ src_arr,
                                                   const float* __restrict__ w2,
                                                   const uint32* __restrict__ h2u,
                                                   const float* __restrict__ b2,
                                                   const int* __restrict__ batch,
                                                   float* __restrict__ pooled) {
    __shared__ float w_sh[4][64];
    __shared__ int src_sh[4][64];
    int tid = threadIdx.x, lane = tid & 63, wv = tid >> 6;
    int i = blockIdx.x * 4 + wv;
    int rs = row_ptr[i], deg = row_ptr[i + 1] - rs;

    f32x2 acc = {0.f, 0.f};
    float den = 0.f;
    if (deg <= 64) {
        if (lane < deg) {
            float w = w2[rs + lane];
            den = w;
            w_sh[wv][lane] = w;
            src_sh[wv][lane] = src_arr[rs + lane];
        }
        __builtin_amdgcn_wave_barrier();
#pragma unroll
        for (int off = 1; off < 64; off <<= 1) den += __shfl_xor(den, off, 64);
        float rden = __builtin_amdgcn_rcpf(den);
        int cnt = deg, eix = 0;
        for (; eix + 1 < cnt; eix += 2) {
            int s0 = src_sh[wv][eix], s1 = src_sh[wv][eix + 1];
            float w0 = w_sh[wv][eix], w1 = w_sh[wv][eix + 1];
            uint32 u0 = h2u[(size_t)s0 * 64 + lane];
            uint32 u1 = h2u[(size_t)s1 * 64 + lane];
            acc = w0 * bf2(u0) + acc;
            acc = w1 * bf2(u1) + acc;
        }
        if (eix < cnt) {
            int s0 = src_sh[wv][eix];
            float w0 = w_sh[wv][eix];
            uint32 u0 = h2u[(size_t)s0 * 64 + lane];
            acc = w0 * bf2(u0) + acc;
        }
        acc *= rden;
    } else {
        for (int eix = lane; eix < deg; eix += 64) den += w2[rs + eix];
#pragma unroll
        for (int off = 1; off < 64; off <<= 1) den += __shfl_xor(den, off, 64);
        float rden = __builtin_amdgcn_rcpf(den);
        for (int base = 0; base < deg; base += 64) {
            int cnt = min(deg - base, 64);
            if (lane < cnt) {
                w_sh[wv][lane] = w2[rs + base + lane];
                src_sh[wv][lane] = src_arr[rs + base + lane];
            }
            __builtin_amdgcn_wave_barrier();
            int eix = 0;
            for (; eix + 1 < cnt; eix += 2) {
                int s0 = src_sh[wv][eix], s1 = src_sh[wv][eix + 1];
                float w0 = w_sh[wv][eix], w1 = w_sh[wv][eix + 1];
                uint32 u0 = h2u[(size_t)s0 * 64 + lane];
                uint32 u1 = h2u[(size_t)s1 * 64 + lane];
                acc = w0 * bf2(u0) + acc;
                acc = w1 * bf2(u1) + acc;
            }
            if (eix < cnt) {
                int s0 = src_sh[wv][eix];
                float w0 = w_sh[wv][eix];
                uint32 u0 = h2u[(size_t)s0 * 64 + lane];
                acc = w0 * bf2(u0) + acc;
            }
            __builtin_amdgcn_wave_barrier();
        }
        acc *= rden;
    }
    float2 bv = ((const float2*)b2)[lane];
    float v0 = fmaxf(acc.x + bv.x, 0.f);
    float v1 = fmaxf(acc.y + bv.y, 0.f);
    int g = batch[i];
    atomicMax((int*)&pooled[g * OUT2 + 2 * lane], __float_as_int(v0));
    atomicMax((int*)&pooled[g * OUT2 + 2 * lane + 1], __float_as_int(v1));
}

// ---------------- final FC + relu ----------------
__global__ __launch_bounds__(128) void fc_kernel(const float* __restrict__ pooled,
                                                 const float* __restrict__ fcW,
                                                 const float* __restrict__ fcb,
                                                 float* __restrict__ out) {
    int g = blockIdx.x, tid = threadIdx.x;
    __shared__ float p[128];
    p[tid] = pooled[g * OUT2 + tid];
    __syncthreads();
    float acc = fcb[tid];
    for (int k = 0; k < 128; ++k) acc = fmaf(p[k], fcW[k * OUT2 + tid], acc);
    out[g * OUT2 + tid] = fmaxf(acc, 0.f);
}

extern "C" void kernel_launch(void* const* d_in, const int* in_sizes, int n_in,
                              void* d_out, int out_size, void* d_ws, size_t ws_size,
                              hipStream_t stream) {
    const float* x      = (const float*)d_in[0];
    const int*   ei     = (const int*)d_in[1];
    const int*   batch  = (const int*)d_in[2];
    const float* W1     = (const float*)d_in[4];
    const float* a_src1 = (const float*)d_in[5];
    const float* a_dst1 = (const float*)d_in[6];
    const float* b1     = (const float*)d_in[7];
    const float* W2     = (const float*)d_in[8];
    const float* a_src2 = (const float*)d_in[9];
    const float* a_dst2 = (const float*)d_in[10];
    const float* b2     = (const float*)d_in[11];
    const float* fcW    = (const float*)d_in[12];
    const float* fcb    = (const float*)d_in[13];
    float* out = (float*)d_out;

    size_t off = 0;
    char* base = (char*)d_ws;
    auto alloc = [&](size_t bytes) -> void* {
        void* p = base + off;
        off += (bytes + 255) & ~(size_t)255;
        return p;
    };
    uint32* aggb = (uint32*)alloc((size_t)N_NODES * 390 * 4);   // head-major [10][N][39u]
    u16* out1   = (u16*)alloc((size_t)N_NODES * D1 * 2);        // head-major [10][N][78]
    u16* h2     = (u16*)alloc((size_t)N_NODES * OUT2 * 2);      // also hosts xb early
    u16* xb     = h2;   // xb dead before gemm2 writes h2
    float* asd1 = (float*)alloc((size_t)N_NODES * 20 * 4);
    float* as2  = (float*)alloc((size_t)N_NODES * 4);
    float* ad2  = (float*)alloc((size_t)N_NODES * 4);
    u16* W1X    = (u16*)alloc((size_t)NW1 * 2);
    u16* W2T    = (u16*)alloc((size_t)NW2 * 2);
    u16* VAT    = (u16*)alloc((size_t)32 * F_INN * 2);
    float* w2as = (float*)alloc((size_t)D1 * 4);
    float* w2ad = (float*)alloc((size_t)D1 * 4);
    float* pooled = (float*)alloc((size_t)NGRAPH * OUT2 * 4);
    int* deg     = (int*)alloc((size_t)N_NODES * 4);
    int* row_ptr = (int*)alloc((size_t)(N_NODES + 1) * 4);
    int* cursor  = (int*)alloc((size_t)N_NODES * 4);
    int* src_arr = (int*)alloc((size_t)ETOT * 4);
    int* dst_arr = (int*)alloc((size_t)ETOT * 4);
    uint32* expw5 = (uint32*)alloc((size_t)ETOT * 5 * 4);
    float* w2e   = (float*)alloc((size_t)ETOT * 4);
    int* bsum    = (int*)alloc(196 * 4);
    int* boff    = (int*)alloc(196 * 4);

    hipMemsetAsync(deg, 0, (size_t)N_NODES * 4, stream);
    hipMemsetAsync(pooled, 0, (size_t)NGRAPH * OUT2 * 4, stream);
    hipMemsetAsync(as2, 0, (size_t)N_NODES * 4, stream);
    hipMemsetAsync(ad2, 0, (size_t)N_NODES * 4, stream);

    prep_kernel<<<2048, 256, 0, stream>>>(x, W1, W2, xb, W1X, W2T);
    prep2_kernel<<<8, 256, 0, stream>>>(W1, a_src1, a_dst1, W2, a_src2, a_dst2,
                                        VAT, w2as, w2ad);
    alphas1x_kernel<<<391, 256, 0, stream>>>(xb, VAT, asd1);
    hist_kernel<<<(ETOT + 255) / 256, 256, 0, stream>>>(ei, deg);
    scan1_kernel<<<196, 256, 0, stream>>>(deg, row_ptr, bsum);
    scan2_kernel<<<1, 256, 0, stream>>>(bsum, boff);
    scan3_kernel<<<196, 256, 0, stream>>>(row_ptr, boff, cursor);
    scatter_kernel<<<(ETOT + 255) / 256, 256, 0, stream>>>(ei, cursor, src_arr, dst_arr);
    expw_kernel<<<(ETOT + 255) / 256, 256, 0, stream>>>(src_arr, dst_arr, asd1, expw5);
    agg1x_kernel<<<N_NODES / 4, 256, 0, stream>>>(row_ptr, src_arr, expw5,
                                                  (const uint32*)xb, aggb);
    gemm1b_kernel<<<dim3(391, 10), 256, 0, stream>>>(aggb, (const uint32*)W1X,
                                                     b1, w2as, w2ad,
                                                     out1, as2, ad2);
    gemm2_mfma<<<782, 256, 0, stream>>>((const uint32*)out1, W2T, h2);
    expw2_kernel<<<(ETOT + 255) / 256, 256, 0, stream>>>(src_arr, dst_arr, as2, ad2, w2e);
    agg2_kernel<<<N_NODES / 4, 256, 0, stream>>>(row_ptr, src_arr, w2e,
                                                 (const uint32*)h2, b2, batch, pooled);
    fc_kernel<<<NGRAPH, 128, 0, stream>>>(pooled, fcW, fcb, out);
}

// Round 10
// 428.435 us; speedup vs baseline: 1.4993x; 1.3637x over previous
//
#include <hip/hip_runtime.h>
#include <hip/hip_bf16.h>
#include <stdint.h>

typedef unsigned int uint32;
typedef unsigned short u16;
typedef __attribute__((ext_vector_type(8))) short bf16x8;
typedef __attribute__((ext_vector_type(4))) float f32x4;
typedef __attribute__((ext_vector_type(2))) float f32x2;
typedef uint32 u32x4 __attribute__((ext_vector_type(4)));

#define N_NODES 50000
#define NP      50048                 // padded row count (391*128)
#define N_EDGES 800000
#define ETOT    (N_EDGES + N_NODES)
#define F_INN   78
#define H1      10
#define D1      780
#define OUT2    128
#define NGRAPH  512
#define NEG_SLOPE 0.2f
#define PL40    ((size_t)NP * 40)     // uints per padded head-plane

__device__ __forceinline__ float lrelu(float v) { return v > 0.f ? v : NEG_SLOPE * v; }
__device__ __forceinline__ u16 f2bfbits(float f) {
    return __bfloat16_as_ushort(__float2bfloat16(f));
}
__device__ __forceinline__ uint32 packbf(float lo, float hi) {
    return (uint32)f2bfbits(lo) | ((uint32)f2bfbits(hi) << 16);
}
__device__ __forceinline__ f32x2 bf2(uint32 u) {
    __hip_bfloat162 b = *reinterpret_cast<__hip_bfloat162*>(&u);
    float2 t = __bfloat1622float2(b);
    return (f32x2){t.x, t.y};
}
__device__ __forceinline__ int esrc(const int* ei, int e) { return e < N_EDGES ? ei[e] : e - N_EDGES; }
__device__ __forceinline__ int edst(const int* ei, int e) { return e < N_EDGES ? ei[N_EDGES + e] : e - N_EDGES; }

// async global->LDS 16B per lane: lane i moves g[lane*16B] -> lds_base + lane*16B
typedef __attribute__((address_space(1))) const uint32 guint;
typedef __attribute__((address_space(3))) uint32 luint;
__device__ __forceinline__ void cp16(uint32* lds, const uint32* g, int lane) {
    __builtin_amdgcn_global_load_lds((guint*)(g + lane * 4), (luint*)lds, 16, 0, 0);
}

// ---------------- prep: xbp [NP][80 u16], w1p [10][80][80 u16], w2p [10][128][80 u16] ----------------
#define NXP (N_NODES * 80)
__global__ __launch_bounds__(256) void prep_kernel(const float* __restrict__ x,
                                                   const float* __restrict__ W1,
                                                   const float* __restrict__ W2,
                                                   u16* __restrict__ xbp,
                                                   u16* __restrict__ w1p,
                                                   u16* __restrict__ w2p) {
    const int total = NXP + 10 * 80 * 80 + 10 * 128 * 80;
    for (int id = blockIdx.x * 256 + threadIdx.x; id < total; id += gridDim.x * 256) {
        if (id < NXP) {
            int n = id / 80, k = id - n * 80;
            xbp[id] = (k < 78) ? f2bfbits(x[n * 78 + k]) : (u16)0;
        } else if (id < NXP + 64000) {
            int t = id - NXP;
            int h = t / 6400, r = t - h * 6400;
            int n = r / 80, k = r - n * 80;
            w1p[t] = (n < 78 && k < 78) ? f2bfbits(W1[k * D1 + h * 78 + n]) : (u16)0;
        } else {
            int t = id - NXP - 64000;
            int h = t / 10240, r = t - h * 10240;
            int n = r / 80, k = r - n * 80;
            w2p[t] = (k < 78) ? f2bfbits(W2[(h * 78 + k) * OUT2 + n]) : (u16)0;
        }
    }
}

// ---------------- prep2: VAT [32][80 u16] padded + w2as/w2ad ----------------
__global__ __launch_bounds__(256) void prep2_kernel(const float* __restrict__ W1,
                                                    const float* __restrict__ a_src1,
                                                    const float* __restrict__ a_dst1,
                                                    const float* __restrict__ W2,
                                                    const float* __restrict__ a_src2,
                                                    const float* __restrict__ a_dst2,
                                                    u16* __restrict__ VAT,
                                                    float* __restrict__ w2as,
                                                    float* __restrict__ w2ad) {
    int gid = blockIdx.x * 256 + threadIdx.x;
    int gs = gridDim.x * 256;
    for (int idx = gid; idx < 32 * 80; idx += gs) {
        int j = idx / 80, k = idx - j * 80;
        float s = 0.f;
        if (j < 20 && k < 78) {
            int h = (j < 10) ? j : j - 10;
            const float* vec = ((j < 10) ? a_src1 : a_dst1) + h * F_INN;
            const float* wrow = W1 + k * D1 + h * F_INN;
            for (int f = 0; f < F_INN; ++f) s = fmaf(wrow[f], vec[f], s);
            VAT[idx] = f2bfbits(s);
        } else {
            VAT[idx] = 0;
        }
    }
    for (int c = gid; c < D1; c += gs) {
        const float* r0 = W2 + (size_t)c * OUT2;
        float s = 0.f, d = 0.f;
        for (int j = 0; j < OUT2; ++j) {
            s = fmaf(r0[j], a_src2[j], s);
            d = fmaf(r0[j], a_dst2[j], d);
        }
        w2as[c] = s;
        w2ad[c] = d;
    }
}

// ---------------- alphas1x: xbp[128 rows] @ VAT^T -> asd1[N][20] ----------------
__global__ __launch_bounds__(256) void alphas1x_kernel(const uint32* __restrict__ xbu,
                                                       const uint32* __restrict__ vatu,
                                                       float* __restrict__ asd1) {
    __shared__ uint32 As[5136];
    __shared__ uint32 Bs[1296];
    int tid = threadIdx.x, lane = tid & 63, wv = tid >> 6;
    int row0 = blockIdx.x * 128;
    const uint32* aplane = xbu + (size_t)row0 * 40;

#pragma unroll
    for (int t = 0; t < 5; ++t)
        cp16(As + wv * 1280 + t * 256, aplane + wv * 1280 + t * 256, lane);
    if (wv == 0) {
#pragma unroll
        for (int t = 0; t < 5; ++t)
            cp16(Bs + t * 256, vatu + t * 256, lane);
    }
    __syncthreads();

    int l15 = lane & 15, quad = lane >> 4;
    const u16* Asu = (const u16*)As;
    const u16* Bsu = (const u16*)Bs;
    f32x4 acc[2][2];
#pragma unroll
    for (int mi = 0; mi < 2; ++mi)
#pragma unroll
        for (int nj = 0; nj < 2; ++nj) acc[mi][nj] = (f32x4){0.f, 0.f, 0.f, 0.f};

    int abase[2], bbase[2];
#pragma unroll
    for (int mi = 0; mi < 2; ++mi) abase[mi] = (wv * 32 + mi * 16 + l15) * 80 + quad * 8;
#pragma unroll
    for (int nj = 0; nj < 2; ++nj) bbase[nj] = (nj * 16 + l15) * 80 + quad * 8;

    bf16x8 z8 = {0, 0, 0, 0, 0, 0, 0, 0};
#pragma unroll
    for (int ks = 0; ks < 96; ks += 32) {
        bf16x8 a[2], b[2];
#pragma unroll
        for (int mi = 0; mi < 2; ++mi) {
            a[mi] = *(const bf16x8*)(Asu + abase[mi] + ks);
            if (ks == 64 && quad >= 2) a[mi] = z8;
        }
#pragma unroll
        for (int nj = 0; nj < 2; ++nj) b[nj] = *(const bf16x8*)(Bsu + bbase[nj] + ks);
#pragma unroll
        for (int mi = 0; mi < 2; ++mi)
#pragma unroll
            for (int nj = 0; nj < 2; ++nj)
                acc[mi][nj] = __builtin_amdgcn_mfma_f32_16x16x32_bf16(a[mi], b[nj], acc[mi][nj], 0, 0, 0);
    }

#pragma unroll
    for (int mi = 0; mi < 2; ++mi)
#pragma unroll
        for (int nj = 0; nj < 2; ++nj) {
            int col = nj * 16 + l15;
            if (col < 20) {
#pragma unroll
                for (int reg = 0; reg < 4; ++reg) {
                    int row = row0 + wv * 32 + mi * 16 + quad * 4 + reg;
                    if (row < N_NODES) asd1[(size_t)row * 20 + col] = acc[mi][nj][reg];
                }
            }
        }
}

// ---------------- CSR build ----------------
__global__ void hist_kernel(const int* __restrict__ ei, int* __restrict__ deg) {
    int e = blockIdx.x * 256 + threadIdx.x;
    if (e < ETOT) atomicAdd(&deg[edst(ei, e)], 1);
}

__global__ __launch_bounds__(256) void scan1_kernel(const int* __restrict__ deg,
                                                    int* __restrict__ row_ptr,
                                                    int* __restrict__ bsum) {
    __shared__ int buf[256];
    int tid = threadIdx.x;
    int i = blockIdx.x * 256 + tid;
    int v = (i < N_NODES) ? deg[i] : 0;
    buf[tid] = v;
    __syncthreads();
    for (int off = 1; off < 256; off <<= 1) {
        int t = (tid >= off) ? buf[tid - off] : 0;
        __syncthreads();
        buf[tid] += t;
        __syncthreads();
    }
    if (i < N_NODES) row_ptr[i] = buf[tid] - v;
    if (tid == 255) bsum[blockIdx.x] = buf[255];
}

__global__ __launch_bounds__(256) void scan2_kernel(const int* __restrict__ bsum,
                                                    int* __restrict__ boff) {
    __shared__ int buf[256];
    int tid = threadIdx.x;
    int v = (tid < 196) ? bsum[tid] : 0;
    buf[tid] = v;
    __syncthreads();
    for (int off = 1; off < 256; off <<= 1) {
        int t = (tid >= off) ? buf[tid - off] : 0;
        __syncthreads();
        buf[tid] += t;
        __syncthreads();
    }
    if (tid < 196) boff[tid] = buf[tid] - v;
}

__global__ __launch_bounds__(256) void scan3_kernel(int* __restrict__ row_ptr,
                                                    const int* __restrict__ boff,
                                                    int* __restrict__ cursor) {
    int i = blockIdx.x * 256 + threadIdx.x;
    if (i < N_NODES) {
        int r = row_ptr[i] + boff[blockIdx.x];
        row_ptr[i] = r;
        cursor[i] = r;
    }
    if (i == 0) row_ptr[N_NODES] = ETOT;
}

__global__ void scatter_kernel(const int* __restrict__ ei, int* __restrict__ cursor,
                               int* __restrict__ src_arr, int* __restrict__ dst_arr) {
    int e = blockIdx.x * 256 + threadIdx.x;
    if (e < ETOT) {
        int d = edst(ei, e);
        int pos = atomicAdd(&cursor[d], 1);
        src_arr[pos] = esrc(ei, e);
        dst_arr[pos] = d;
    }
}

// ---------------- edge-parallel exp weights, layer 1 ----------------
__global__ __launch_bounds__(256) void expw_kernel(const int* __restrict__ src_arr,
                                                   const int* __restrict__ dst_arr,
                                                   const float* __restrict__ asd1,
                                                   uint32* __restrict__ expw5) {
    int p = blockIdx.x * 256 + threadIdx.x;
    if (p >= ETOT) return;
    int s = src_arr[p], d = dst_arr[p];
    const float4* sp = (const float4*)(asd1 + (size_t)s * 20);
    float4 s01 = sp[0], s02 = sp[1];
    float2 s03 = ((const float2*)sp)[4];
    const float* dp = asd1 + (size_t)d * 20 + 10;
    float2 d01 = *(const float2*)dp;
    float4 d02 = *(const float4*)(dp + 2);
    float4 d03 = *(const float4*)(dp + 6);
    float sv[10] = {s01.x, s01.y, s01.z, s01.w, s02.x, s02.y, s02.z, s02.w, s03.x, s03.y};
    float dv[10] = {d01.x, d01.y, d02.x, d02.y, d02.z, d02.w, d03.x, d03.y, d03.z, d03.w};
    uint32 o[5];
#pragma unroll
    for (int k = 0; k < 5; ++k) {
        float w0 = __expf(lrelu(sv[2 * k] + dv[2 * k]));
        float w1 = __expf(lrelu(sv[2 * k + 1] + dv[2 * k + 1]));
        o[k] = packbf(w0, w1);
    }
#pragma unroll
    for (int k = 0; k < 5; ++k) expw5[(size_t)p * 5 + k] = o[k];
}

// ---------------- edge-parallel exp weights, layer 2 ----------------
__global__ __launch_bounds__(256) void expw2_kernel(const int* __restrict__ src_arr,
                                                    const int* __restrict__ dst_arr,
                                                    const float* __restrict__ as2,
                                                    const float* __restrict__ ad2,
                                                    float* __restrict__ w2) {
    int p = blockIdx.x * 256 + threadIdx.x;
    if (p >= ETOT) return;
    w2[p] = __expf(lrelu(as2[src_arr[p]] + ad2[dst_arr[p]]));
}

// ---------------- agg1x: head-major padded output aggb[h][n][40u] ----------------
__global__ __launch_bounds__(256) void agg1x_kernel(const int* __restrict__ row_ptr,
                                                    const int* __restrict__ src_arr,
                                                    const uint32* __restrict__ expw5,
                                                    const uint32* __restrict__ xbu,
                                                    uint32* __restrict__ aggb) {
    __shared__ uint32 rows_sh[4][32 * 40];
    __shared__ float wts_sh[4][32 * 12 + 16];
    int tid = threadIdx.x, lane = tid & 63, wv = tid >> 6;
    int i = blockIdx.x * 4 + wv;
    int rs = row_ptr[i], deg = row_ptr[i + 1] - rs;
    uint32* rows = rows_sh[wv];
    float* wts = wts_sh[wv];
    float* dsh = wts + 32 * 12;

    int hA = (6 * lane) / 39;
    int hB = (6 * lane + 5) / 39;
    int j[6];
    bool sel[6];
#pragma unroll
    for (int q = 0; q < 6; ++q) {
        int u = 6 * lane + q;
        int h = u / 39;
        j[q] = u - 39 * h;
        sel[q] = (h != hA);
    }
    bool tl = lane < 6;
    int jT = 33 + lane;

    f32x2 acc[6];
#pragma unroll
    for (int q = 0; q < 6; ++q) acc[q] = (f32x2){0.f, 0.f};
    f32x2 accT = {0.f, 0.f};
    float den[10];
#pragma unroll
    for (int h = 0; h < 10; ++h) den[h] = 0.f;

    for (int base = 0; base < deg; base += 32) {
        int cnt = min(deg - base, 32);
        int e = lane >> 1, half = lane & 1;
        if (e < cnt) {
            int sn = src_arr[rs + base + e];
            const uint32* rp = xbu + (size_t)sn * 40 + half * 20;
            uint32* lp = rows + e * 40 + half * 20;
#pragma unroll
            for (int t = 0; t < 5; ++t)
                *(u32x4*)(lp + 4 * t) = *(const u32x4*)(rp + 4 * t);
            if (half == 0) {
                const uint32* wp = expw5 + (size_t)(rs + base + e) * 5;
#pragma unroll
                for (int k = 0; k < 5; ++k) {
                    f32x2 w2v = bf2(wp[k]);
                    den[2 * k] += w2v.x;
                    den[2 * k + 1] += w2v.y;
                    *(f32x2*)(wts + e * 12 + 2 * k) = w2v;
                }
            }
        }
        __builtin_amdgcn_wave_barrier();
        for (int e2 = 0; e2 < cnt; ++e2) {
            const uint32* rb = rows + e2 * 40;
            const float* wb = wts + e2 * 12;
            float wA = wb[hA], wBv = wb[hB];
#pragma unroll
            for (int q = 0; q < 6; ++q) {
                uint32 v = rb[j[q]];
                float w = sel[q] ? wBv : wA;
                acc[q] = w * bf2(v) + acc[q];
            }
            if (tl) {
                uint32 v = rb[jT];
                accT = wb[9] * bf2(v) + accT;
            }
        }
        __builtin_amdgcn_wave_barrier();
    }

#pragma unroll
    for (int off = 1; off < 64; off <<= 1)
#pragma unroll
        for (int h = 0; h < 10; ++h) den[h] += __shfl_xor(den[h], off, 64);
    if (lane < 10) dsh[lane] = den[lane];
    __builtin_amdgcn_wave_barrier();
    float rA = __builtin_amdgcn_rcpf(dsh[hA]);
    float rB = __builtin_amdgcn_rcpf(dsh[hB]);
    float r9 = __builtin_amdgcn_rcpf(dsh[9]);

    size_t nbase = (size_t)i * 40;
#pragma unroll
    for (int q = 0; q < 6; ++q) {
        f32x2 a = acc[q] * (sel[q] ? rB : rA);
        int hh = sel[q] ? hB : hA;
        aggb[(size_t)hh * PL40 + nbase + j[q]] = packbf(a.x, a.y);
    }
    if (tl) {
        f32x2 a = accT * r9;
        aggb[(size_t)9 * PL40 + nbase + jT] = packbf(a.x, a.y);
    }
}

// ---------------- gemm1b v4: async staging, coalesced writeback, no atomics ----------------
__global__ __launch_bounds__(256) void gemm1b_kernel(const uint32* __restrict__ aggb,
                                                     const uint32* __restrict__ w1p,
                                                     const float* __restrict__ b1,
                                                     const float* __restrict__ w2as,
                                                     const float* __restrict__ w2ad,
                                                     uint32* __restrict__ out1p,
                                                     float* __restrict__ asp,
                                                     float* __restrict__ adp) {
    __shared__ uint32 As[5136];
    __shared__ uint32 Bs[3336];
    int tid = threadIdx.x, lane = tid & 63, wv = tid >> 6;
    int row0 = blockIdx.x * 128;
    int h = blockIdx.y;
    const uint32* aplane = aggb + (size_t)h * PL40 + (size_t)row0 * 40;
    const uint32* wplane = w1p + (size_t)h * 3200;

#pragma unroll
    for (int t = 0; t < 5; ++t)
        cp16(As + wv * 1280 + t * 256, aplane + wv * 1280 + t * 256, lane);
    int tw0 = wv * 3, tw1 = (wv == 3) ? 13 : wv * 3 + 3;
    for (int t = tw0; t < tw1; ++t)
        cp16(Bs + t * 256, wplane + t * 256, lane);
    __syncthreads();

    int l15 = lane & 15, quad = lane >> 4;
    const u16* Asu = (const u16*)As;
    const u16* Bsu = (const u16*)Bs;

    f32x4 acc[2][5];
#pragma unroll
    for (int mi = 0; mi < 2; ++mi)
#pragma unroll
        for (int nj = 0; nj < 5; ++nj) acc[mi][nj] = (f32x4){0.f, 0.f, 0.f, 0.f};

    int abase[2], bbase[5];
#pragma unroll
    for (int mi = 0; mi < 2; ++mi) abase[mi] = (wv * 32 + mi * 16 + l15) * 80 + quad * 8;
#pragma unroll
    for (int nj = 0; nj < 5; ++nj) bbase[nj] = (nj * 16 + l15) * 80 + quad * 8;

    bf16x8 z8 = {0, 0, 0, 0, 0, 0, 0, 0};
#pragma unroll
    for (int ks = 0; ks < 96; ks += 32) {
        bf16x8 a[2], b[5];
#pragma unroll
        for (int mi = 0; mi < 2; ++mi) {
            a[mi] = *(const bf16x8*)(Asu + abase[mi] + ks);
            if (ks == 64 && quad >= 2) a[mi] = z8;
        }
#pragma unroll
        for (int nj = 0; nj < 5; ++nj) b[nj] = *(const bf16x8*)(Bsu + bbase[nj] + ks);
#pragma unroll
        for (int mi = 0; mi < 2; ++mi)
#pragma unroll
            for (int nj = 0; nj < 5; ++nj)
                acc[mi][nj] = __builtin_amdgcn_mfma_f32_16x16x32_bf16(a[mi], b[nj], acc[mi][nj], 0, 0, 0);
    }

    __syncthreads();   // As reads complete; reuse As as C buffer
    u16* Cw = (u16*)As;
    float s2p[2][4] = {}, d2p[2][4] = {};
#pragma unroll
    for (int mi = 0; mi < 2; ++mi) {
        int rl0 = wv * 32 + mi * 16 + quad * 4;
#pragma unroll
        for (int nj = 0; nj < 5; ++nj) {
            int col = nj * 16 + l15;
            if (col < 78) {
                int gc = h * 78 + col;
                float bia = b1[gc], was = w2as[gc], wad = w2ad[gc];
#pragma unroll
                for (int reg = 0; reg < 4; ++reg) {
                    float v = fmaxf(acc[mi][nj][reg] + bia, 0.f);
                    Cw[(rl0 + reg) * 80 + col] = f2bfbits(v);
                    s2p[mi][reg] = fmaf(v, was, s2p[mi][reg]);
                    d2p[mi][reg] = fmaf(v, wad, d2p[mi][reg]);
                }
            } else {
#pragma unroll
                for (int reg = 0; reg < 4; ++reg) Cw[(rl0 + reg) * 80 + col] = 0;
            }
        }
    }
#pragma unroll
    for (int off = 1; off < 16; off <<= 1)
#pragma unroll
        for (int mi = 0; mi < 2; ++mi)
#pragma unroll
            for (int reg = 0; reg < 4; ++reg) {
                s2p[mi][reg] += __shfl_xor(s2p[mi][reg], off, 64);
                d2p[mi][reg] += __shfl_xor(d2p[mi][reg], off, 64);
            }
    if (l15 == 0) {
#pragma unroll
        for (int mi = 0; mi < 2; ++mi) {
            int rowb = row0 + wv * 32 + mi * 16 + quad * 4;
#pragma unroll
            for (int reg = 0; reg < 4; ++reg) {
                int r = rowb + reg;
                if (r < N_NODES) {
                    asp[(size_t)h * N_NODES + r] = s2p[mi][reg];
                    adp[(size_t)h * N_NODES + r] = d2p[mi][reg];
                }
            }
        }
    }
    __syncthreads();
    // coalesced copy As -> out1p (5120 uints)
    uint32* oplane = out1p + (size_t)h * PL40 + (size_t)row0 * 40;
#pragma unroll
    for (int jj = 0; jj < 5; ++jj) {
        int idx = jj * 256 + tid;
        *(u32x4*)(oplane + 4 * idx) = *(const u32x4*)(As + 4 * idx);
    }
}

// ---------------- sum10: as2/ad2 = sum over heads of partials ----------------
__global__ __launch_bounds__(256) void sum10_kernel(const float* __restrict__ asp,
                                                    const float* __restrict__ adp,
                                                    float* __restrict__ as2,
                                                    float* __restrict__ ad2) {
    int n = blockIdx.x * 256 + threadIdx.x;
    if (n >= N_NODES) return;
    float s = 0.f, d = 0.f;
#pragma unroll
    for (int h = 0; h < 10; ++h) {
        s += asp[(size_t)h * N_NODES + n];
        d += adp[(size_t)h * N_NODES + n];
    }
    as2[n] = s;
    ad2[n] = d;
}

// ---------------- gemm2 v3: 64-row blocks, per-head async-staged K-loop ----------------
__global__ __launch_bounds__(256) void gemm2_mfma(const uint32* __restrict__ out1p,
                                                  const uint32* __restrict__ w2p,
                                                  u16* __restrict__ h2) {
    __shared__ uint32 As[2576];
    __shared__ uint32 Bs[5136];
    int tid = threadIdx.x, lane = tid & 63, wv = tid >> 6;
    int row0 = blockIdx.x * 64;
    int l15 = lane & 15, quad = lane >> 4;
    const u16* Asu = (const u16*)As;
    const u16* Bsu = (const u16*)Bs;

    f32x4 acc[8];
#pragma unroll
    for (int nj = 0; nj < 8; ++nj) acc[nj] = (f32x4){0.f, 0.f, 0.f, 0.f};

    int abase = (wv * 16 + l15) * 80 + quad * 8;
    int bbase[8];
#pragma unroll
    for (int nj = 0; nj < 8; ++nj) bbase[nj] = (nj * 16 + l15) * 80 + quad * 8;
    bf16x8 z8 = {0, 0, 0, 0, 0, 0, 0, 0};

    for (int h = 0; h < 10; ++h) {
        const uint32* aplane = out1p + (size_t)h * PL40 + (size_t)row0 * 40;
        const uint32* bplane = w2p + (size_t)h * 5120;
        for (int t = wv; t < 10; t += 4)
            cp16(As + t * 256, aplane + t * 256, lane);
#pragma unroll
        for (int t = 0; t < 5; ++t)
            cp16(Bs + (wv * 5 + t) * 256, bplane + (wv * 5 + t) * 256, lane);
        __syncthreads();
#pragma unroll
        for (int ks = 0; ks < 96; ks += 32) {
            bf16x8 a = *(const bf16x8*)(Asu + abase + ks);
            if (ks == 64 && quad >= 2) a = z8;
#pragma unroll
            for (int nj = 0; nj < 8; ++nj) {
                bf16x8 b = *(const bf16x8*)(Bsu + bbase[nj] + ks);
                acc[nj] = __builtin_amdgcn_mfma_f32_16x16x32_bf16(a, b, acc[nj], 0, 0, 0);
            }
        }
        __syncthreads();
    }

#pragma unroll
    for (int nj = 0; nj < 8; ++nj) {
        int col = nj * 16 + l15;
#pragma unroll
        for (int reg = 0; reg < 4; ++reg) {
            int r = row0 + wv * 16 + quad * 4 + reg;
            if (r < N_NODES) h2[(size_t)r * OUT2 + col] = f2bfbits(acc[nj][reg]);
        }
    }
}

// ---------------- layer-2 aggregation + pool ----------------
__global__ __launch_bounds__(256) void agg2_kernel(const int* __restrict__ row_ptr,
                                                   const int* __restrict__ src_arr,
                                                   const float* __restrict__ w2,
                                                   const uint32* __restrict__ h2u,
                                                   const float* __restrict__ b2,
                                                   const int* __restrict__ batch,
                                                   float* __restrict__ pooled) {
    __shared__ float w_sh[4][64];
    __shared__ int src_sh[4][64];
    int tid = threadIdx.x, lane = tid & 63, wv = tid >> 6;
    int i = blockIdx.x * 4 + wv;
    int rs = row_ptr[i], deg = row_ptr[i + 1] - rs;

    f32x2 acc = {0.f, 0.f};
    float den = 0.f;
    if (deg <= 64) {
        if (lane < deg) {
            float w = w2[rs + lane];
            den = w;
            w_sh[wv][lane] = w;
            src_sh[wv][lane] = src_arr[rs + lane];
        }
        __builtin_amdgcn_wave_barrier();
#pragma unroll
        for (int off = 1; off < 64; off <<= 1) den += __shfl_xor(den, off, 64);
        float rden = __builtin_amdgcn_rcpf(den);
        int cnt = deg, eix = 0;
        for (; eix + 1 < cnt; eix += 2) {
            int s0 = src_sh[wv][eix], s1 = src_sh[wv][eix + 1];
            float w0 = w_sh[wv][eix], w1 = w_sh[wv][eix + 1];
            uint32 u0 = h2u[(size_t)s0 * 64 + lane];
            uint32 u1 = h2u[(size_t)s1 * 64 + lane];
            acc = w0 * bf2(u0) + acc;
            acc = w1 * bf2(u1) + acc;
        }
        if (eix < cnt) {
            int s0 = src_sh[wv][eix];
            float w0 = w_sh[wv][eix];
            uint32 u0 = h2u[(size_t)s0 * 64 + lane];
            acc = w0 * bf2(u0) + acc;
        }
        acc *= rden;
    } else {
        for (int eix = lane; eix < deg; eix += 64) den += w2[rs + eix];
#pragma unroll
        for (int off = 1; off < 64; off <<= 1) den += __shfl_xor(den, off, 64);
        float rden = __builtin_amdgcn_rcpf(den);
        for (int base = 0; base < deg; base += 64) {
            int cnt = min(deg - base, 64);
            if (lane < cnt) {
                w_sh[wv][lane] = w2[rs + base + lane];
                src_sh[wv][lane] = src_arr[rs + base + lane];
            }
            __builtin_amdgcn_wave_barrier();
            int eix = 0;
            for (; eix + 1 < cnt; eix += 2) {
                int s0 = src_sh[wv][eix], s1 = src_sh[wv][eix + 1];
                float w0 = w_sh[wv][eix], w1 = w_sh[wv][eix + 1];
                uint32 u0 = h2u[(size_t)s0 * 64 + lane];
                uint32 u1 = h2u[(size_t)s1 * 64 + lane];
                acc = w0 * bf2(u0) + acc;
                acc = w1 * bf2(u1) + acc;
            }
            if (eix < cnt) {
                int s0 = src_sh[wv][eix];
                float w0 = w_sh[wv][eix];
                uint32 u0 = h2u[(size_t)s0 * 64 + lane];
                acc = w0 * bf2(u0) + acc;
            }
            __builtin_amdgcn_wave_barrier();
        }
        acc *= rden;
    }
    float2 bv = ((const float2*)b2)[lane];
    float v0 = fmaxf(acc.x + bv.x, 0.f);
    float v1 = fmaxf(acc.y + bv.y, 0.f);
    int g = batch[i];
    atomicMax((int*)&pooled[g * OUT2 + 2 * lane], __float_as_int(v0));
    atomicMax((int*)&pooled[g * OUT2 + 2 * lane + 1], __float_as_int(v1));
}

// ---------------- final FC + relu ----------------
__global__ __launch_bounds__(128) void fc_kernel(const float* __restrict__ pooled,
                                                 const float* __restrict__ fcW,
                                                 const float* __restrict__ fcb,
                                                 float* __restrict__ out) {
    int g = blockIdx.x, tid = threadIdx.x;
    __shared__ float p[128];
    p[tid] = pooled[g * OUT2 + tid];
    __syncthreads();
    float acc = fcb[tid];
    for (int k = 0; k < 128; ++k) acc = fmaf(p[k], fcW[k * OUT2 + tid], acc);
    out[g * OUT2 + tid] = fmaxf(acc, 0.f);
}

extern "C" void kernel_launch(void* const* d_in, const int* in_sizes, int n_in,
                              void* d_out, int out_size, void* d_ws, size_t ws_size,
                              hipStream_t stream) {
    const float* x      = (const float*)d_in[0];
    const int*   ei     = (const int*)d_in[1];
    const int*   batch  = (const int*)d_in[2];
    const float* W1     = (const float*)d_in[4];
    const float* a_src1 = (const float*)d_in[5];
    const float* a_dst1 = (const float*)d_in[6];
    const float* b1     = (const float*)d_in[7];
    const float* W2     = (const float*)d_in[8];
    const float* a_src2 = (const float*)d_in[9];
    const float* a_dst2 = (const float*)d_in[10];
    const float* b2     = (const float*)d_in[11];
    const float* fcW    = (const float*)d_in[12];
    const float* fcb    = (const float*)d_in[13];
    float* out = (float*)d_out;

    size_t off = 0;
    char* base = (char*)d_ws;
    auto alloc = [&](size_t bytes) -> void* {
        void* p = base + off;
        off += (bytes + 255) & ~(size_t)255;
        return p;
    };
    uint32* aggb  = (uint32*)alloc(PL40 * 10 * 4);            // [10][NP][40u]; w2e aliases later
    uint32* out1p = (uint32*)alloc(PL40 * 10 * 4);            // [10][NP][40u]
    u16* h2arena  = (u16*)alloc((size_t)N_NODES * OUT2 * 2);  // h2; xbp aliases early
    u16* h2   = h2arena;
    u16* xbp  = h2arena;                                      // [NP][80 u16] = 8.0 MB < 12.8 MB ✓
    float* asd1 = (float*)alloc((size_t)N_NODES * 20 * 4);    // asp/adp alias after expw
    float* asp  = asd1;
    float* adp  = asd1 + (size_t)10 * N_NODES;
    float* as2  = (float*)alloc((size_t)N_NODES * 4);
    float* ad2  = (float*)alloc((size_t)N_NODES * 4);
    u16* w1p    = (u16*)alloc((size_t)(10 * 80 * 80) * 2 + 1024);  // + stage slack
    u16* w2p    = (u16*)alloc((size_t)(10 * 128 * 80) * 2);
    u16* VAT    = (u16*)alloc((size_t)32 * 80 * 2);
    float* w2as = (float*)alloc((size_t)D1 * 4);
    float* w2ad = (float*)alloc((size_t)D1 * 4);
    float* pooled = (float*)alloc((size_t)NGRAPH * OUT2 * 4);
    int* deg     = (int*)alloc((size_t)N_NODES * 4);
    int* row_ptr = (int*)alloc((size_t)(N_NODES + 1) * 4);
    int* cursor  = (int*)alloc((size_t)N_NODES * 4);
    int* src_arr = (int*)alloc((size_t)ETOT * 4);
    int* dst_arr = (int*)alloc((size_t)ETOT * 4);
    uint32* expw5 = (uint32*)alloc((size_t)ETOT * 5 * 4);
    int* bsum    = (int*)alloc(196 * 4);
    int* boff    = (int*)alloc(196 * 4);
    float* w2e   = (float*)aggb;                              // aggb dead after gemm1b

    hipMemsetAsync(deg, 0, (size_t)N_NODES * 4, stream);
    hipMemsetAsync(pooled, 0, (size_t)NGRAPH * OUT2 * 4, stream);

    prep_kernel<<<2048, 256, 0, stream>>>(x, W1, W2, xbp, w1p, w2p);
    prep2_kernel<<<8, 256, 0, stream>>>(W1, a_src1, a_dst1, W2, a_src2, a_dst2,
                                        VAT, w2as, w2ad);
    alphas1x_kernel<<<391, 256, 0, stream>>>((const uint32*)xbp, (const uint32*)VAT, asd1);
    hist_kernel<<<(ETOT + 255) / 256, 256, 0, stream>>>(ei, deg);
    scan1_kernel<<<196, 256, 0, stream>>>(deg, row_ptr, bsum);
    scan2_kernel<<<1, 256, 0, stream>>>(bsum, boff);
    scan3_kernel<<<196, 256, 0, stream>>>(row_ptr, boff, cursor);
    scatter_kernel<<<(ETOT + 255) / 256, 256, 0, stream>>>(ei, cursor, src_arr, dst_arr);
    expw_kernel<<<(ETOT + 255) / 256, 256, 0, stream>>>(src_arr, dst_arr, asd1, expw5);
    agg1x_kernel<<<N_NODES / 4, 256, 0, stream>>>(row_ptr, src_arr, expw5,
                                                  (const uint32*)xbp, aggb);
    gemm1b_kernel<<<dim3(391, 10), 256, 0, stream>>>(aggb, (const uint32*)w1p,
                                                     b1, w2as, w2ad,
                                                     out1p, asp, adp);
    sum10_kernel<<<196, 256, 0, stream>>>(asp, adp, as2, ad2);
    gemm2_mfma<<<782, 256, 0, stream>>>(out1p, (const uint32*)w2p, h2);
    expw2_kernel<<<(ETOT + 255) / 256, 256, 0, stream>>>(src_arr, dst_arr, as2, ad2, w2e);
    agg2_kernel<<<N_NODES / 4, 256, 0, stream>>>(row_ptr, src_arr, w2e,
                                                 (const uint32*)h2, b2, batch, pooled);
    fc_kernel<<<NGRAPH, 128, 0, stream>>>(pooled, fcW, fcb, out);
}